// Round 5
// baseline (479.445 us; speedup 1.0000x reference)
//
#include <hip/hip_runtime.h>

typedef unsigned short u16;
typedef __bf16 bf16x8 __attribute__((ext_vector_type(8)));
typedef float f32x4 __attribute__((ext_vector_type(4)));
typedef u16 u16x8 __attribute__((ext_vector_type(8)));

union B8 { u16x8 u; bf16x8 b; };

__device__ __forceinline__ u16 f2b(float f){
  unsigned u = __float_as_uint(f);
  return (u16)((u + 0x7FFFu + ((u >> 16) & 1u)) >> 16);
}
__device__ __forceinline__ float b2f(u16 h){ return __uint_as_float(((unsigned)h) << 16); }

__device__ __forceinline__ void gload16(const u16* g, u16* l){
  __builtin_amdgcn_global_load_lds((const __attribute__((address_space(1))) void*)g,
                                   (__attribute__((address_space(3))) void*)l, 16, 0, 0);
}

// ---------------- prep kernel ----------------
// blocks: [0,4096) v->v_b single | [4096,4608) Wv->Wv_b single |
//         [4608,5120) transpose+dual-split Wq->WqT_pair, Wk->WkT_pair
__global__ __launch_bounds__(256) void prep_kernel(
    const float* __restrict__ v, const float* __restrict__ Wv,
    const float* __restrict__ Wq, const float* __restrict__ Wk,
    u16* __restrict__ v_b, u16* __restrict__ Wv_b,
    u16* __restrict__ WqT_pair, u16* __restrict__ WkT_pair)
{
  __shared__ float lds[64][65];
  const int blk = blockIdx.x, t = threadIdx.x;
  if (blk < 4608){
    const float* src; u16* dst; long base;
    if (blk < 4096){ src = v;  dst = v_b;  base = blk; }
    else           { src = Wv; dst = Wv_b; base = blk - 4096; }
    long i = base * 256 + t;
    float4 x0 = ((const float4*)src)[2 * i];
    float4 x1 = ((const float4*)src)[2 * i + 1];
    float xs[8] = {x0.x, x0.y, x0.z, x0.w, x1.x, x1.y, x1.z, x1.w};
    u16x8 h;
    #pragma unroll
    for (int j = 0; j < 8; j++) h[j] = f2b(xs[j]);
    ((u16x8*)dst)[i] = h;
  } else {
    int tt = blk - 4608;
    const float* W = (tt >> 8) ? Wk : Wq;
    u16* outp      = (tt >> 8) ? WkT_pair : WqT_pair;
    int t16 = tt & 255, g0 = (t16 >> 4) * 64, f0 = (t16 & 15) * 64;
    int c4 = (t & 15) * 4, r0 = t >> 4;
    #pragma unroll
    for (int it = 0; it < 4; it++){
      int r = r0 + it * 16;
      float4 x = *(const float4*)&W[(long)(g0 + r) * 1024 + f0 + c4];
      lds[r][c4] = x.x; lds[r][c4+1] = x.y; lds[r][c4+2] = x.z; lds[r][c4+3] = x.w;
    }
    __syncthreads();
    #pragma unroll
    for (int it = 0; it < 2; it++){
      int task = t + it * 256;           // 512 tasks = 64 f-rows x 8 g-groups
      int fl = task >> 3, gi = task & 7;
      u16x8 h, l;
      #pragma unroll
      for (int jj = 0; jj < 8; jj++){
        float xv = lds[gi * 8 + jj][fl];
        h[jj] = f2b(xv); l[jj] = f2b(xv - b2f(h[jj]));
      }
      u16* o = outp + (long)(f0 + fl) * 2048 + ((g0 >> 3) + gi) * 16;
      *(u16x8*)o = h;
      *(u16x8*)(o + 8) = l;
    }
  }
}

// ---------------- b[e] = sum_g Wk[g][e] * bq[g], from WkT_pair (hi+lo = fp32-ish) ----
__global__ __launch_bounds__(256) void bvec_kernel(
    const u16* __restrict__ WkT_pair, const float* __restrict__ bq, float* __restrict__ b)
{
  const int wave = threadIdx.x >> 6, lane = threadIdx.x & 63;
  const int e = blockIdx.x * 4 + wave;
  const u16* row = WkT_pair + (long)e * 2048;
  float acc = 0.f;
  #pragma unroll
  for (int ii = 0; ii < 2; ii++){
    int gi = lane * 2 + ii;            // 8-group index 0..127
    const u16* p = row + gi * 16;
    #pragma unroll
    for (int j = 0; j < 8; j++)
      acc += (b2f(p[j]) + b2f(p[j + 8])) * bq[gi * 8 + j];
  }
  #pragma unroll
  for (int off = 32; off > 0; off >>= 1) acc += __shfl_xor(acc, off, 64);
  if (lane == 0) b[e] = acc;
}

// ---------------- split q,k (dual paired) + kb[row] = k_row . b ----------------
__global__ __launch_bounds__(256) void split_qk_kernel(
    const float* __restrict__ q, const float* __restrict__ kk,
    const float* __restrict__ b,
    u16* __restrict__ q_pair, u16* __restrict__ k_pair, float* __restrict__ kb)
{
  const int blk = blockIdx.x, t = threadIdx.x;
  const bool isK = blk >= 4096;
  const float* src = isK ? kk : q;
  u16* dst = isK ? k_pair : q_pair;
  long base = isK ? blk - 4096 : blk;
  long i = base * 256 + t;
  float4 x0 = ((const float4*)src)[2 * i];
  float4 x1 = ((const float4*)src)[2 * i + 1];
  float xs[8] = {x0.x, x0.y, x0.z, x0.w, x1.x, x1.y, x1.z, x1.w};
  u16x8 h, l;
  #pragma unroll
  for (int j = 0; j < 8; j++){ h[j] = f2b(xs[j]); l[j] = f2b(xs[j] - b2f(h[j])); }
  ((u16x8*)dst)[2 * i]     = h;
  ((u16x8*)dst)[2 * i + 1] = l;
  if (isK){
    const int f = (t & 127) * 8;
    float d = 0.f;
    #pragma unroll
    for (int j = 0; j < 8; j++) d += xs[j] * b[f + j];
    #pragma unroll
    for (int off = 32; off > 0; off >>= 1) d += __shfl_xor(d, off, 64);
    __shared__ float red[4];
    if ((t & 63) == 0) red[t >> 6] = d;
    __syncthreads();
    if (t == 0)   kb[base * 2]     = red[0] + red[1];
    if (t == 128) kb[base * 2 + 1] = red[2] + red[3];
  }
}

// ---------------- reduce 4 fp32 partials -> dual pair ----------------
__global__ __launch_bounds__(256) void reduce_split_kernel(
    const float* __restrict__ part, u16* __restrict__ out_pair, long nper)
{
  long i = (long)blockIdx.x * 256 + threadIdx.x;   // 8-elem group index
  float s[8];
  #pragma unroll
  for (int j = 0; j < 8; j++) s[j] = 0.f;
  #pragma unroll
  for (int z = 0; z < 4; z++){
    float4 a0 = ((const float4*)(part + z * nper))[2 * i];
    float4 a1 = ((const float4*)(part + z * nper))[2 * i + 1];
    s[0]+=a0.x; s[1]+=a0.y; s[2]+=a0.z; s[3]+=a0.w;
    s[4]+=a1.x; s[5]+=a1.y; s[6]+=a1.z; s[7]+=a1.w;
  }
  u16x8 h, l;
  #pragma unroll
  for (int j = 0; j < 8; j++){ h[j] = f2b(s[j]); l[j] = f2b(s[j] - b2f(h[j])); }
  long e = (i * 8) >> 10;
  long g = i & 127;
  u16* o = out_pair + e * 2048 + g * 16;
  *(u16x8*)o = h;
  *(u16x8*)(o + 8) = l;
}

// ---------------- XCD-aware block remap (verified R3: FETCH 368->71 MB) ----------------
__device__ __forceinline__ void xcd_remap(int& tx, int& ty, int& tz){
  const int GX = gridDim.x, GY = gridDim.y;
  int b  = blockIdx.x + GX * (blockIdx.y + GY * blockIdx.z);
  int NB = GX * GY * gridDim.z;
  int rank = (b & 7) * (NB >> 3) + (b >> 3);
  int pz = GX * GY;
  tz = rank / pz;
  int r = rank - tz * pz;
  ty = r / GX;
  tx = r - ty * GX;
}

// ---------------- NT GEMM body: C[m][n] = sum_k A[m][k] * B[n][k] ----------------
// EPI: 0 = +bias[n] (nullable), write paired hi|lo (batched by sOb)
//      2 = (+ per-(z,n) col bias if non-null) write fp32 C (batched by sOb)
//      3 = + residual, write fp32 C (batched)
//      4 = +bias[m], write bf16 batch-transposed: out[(n/seq)][m][n%seq] (coalesced in n)
// ADIR (DUAL only): A-fragments read DIRECTLY global->VGPR (no LDS staging for A).
//   Rationale (R4 counters): per 128^2xK32 unit = 1680 cyc; MFMA issue only 14%;
//   LDS 96KB/unit = 58B/cyc; rest = vmcnt(0)-drain serialization. ADIR halves both
//   staged bytes (drain) and LDS reads, kills A-side bank conflicts. A-panel is
//   L2-resident (reused by 16 N-blocks). Values + MFMA order bitwise-identical.
constexpr int BM = 128, BN = 128, BK = 32;

__device__ __forceinline__ int lds1_idx(int row, int g){ return row * 32 + g * 8; }
__device__ __forceinline__ int lds2_idx(int row, int g){
  return row * 64 + (((g ^ (row & 7)) & 7) << 3);
}

// NOTE: 4 blocks/CU for the staged paths. R6's (256,8) capped the unified VGPR+AGPR
// budget at 64/wave -> acc[4][4] spilled to scratch. Do not raise. R2/R3: 256^2
// 1-block/CU pipelined variants measured 101/95 us vs this structure's 90 us ->
// keep 128^2 multi-block (cross-block overlap beats 8-wave lockstep phases).
template<bool DUAL, int EPI, bool ADIR>
__device__ __forceinline__ void gemm_nt_body(
    int tx, int ty, int tz, u16* __restrict__ lds0, u16* __restrict__ lds1,
    const u16* __restrict__ A, const u16* __restrict__ Bm,
    const float* __restrict__ bias, const float* __restrict__ residual,
    void* __restrict__ out0,
    int M, int N, int K, int Krow,
    long sAb, long sBb, long sOb, long sRb, int seq)
{
  const int t = threadIdx.x;
  const int tileM = ty * BM;
  const int tileN = tx * BN;
  const long rs = DUAL ? 2L * Krow : (long)Krow;

  const u16* gA = A  + tz * sAb + (long)tileM * rs;
  const u16* gB = Bm + tz * sBb + (long)tileN * rs;

  const int wave = t >> 6, lane = t & 63;
  const int wm = (wave >> 1) * 64, wn = (wave & 1) * 64;
  const int lr = lane & 15;
  const int lg = lane >> 4;

  const u16 *pa = nullptr, *pb;
  long jstride;
  int  ldsbase, ldsstep, nissue, kadv;
  if (DUAL){
    const int lr8 = lane >> 3, sl = lane & 7;
    const int g = sl ^ lr8;
    if (!ADIR) pa = gA + (long)(wave * 32 + lr8) * rs + g * 8;
    pb = gB + (long)(wave * 32 + lr8) * rs + g * 8;
    jstride = 8 * rs;
    ldsbase = (wave * 32) * 64; ldsstep = 8 * 64;
    nissue = 4; kadv = 64;
  } else {
    pa = gA + (long)(wave * 32 + (lane >> 2)) * rs + (lane & 3) * 8;
    pb = gB + (long)(wave * 32 + (lane >> 2)) * rs + (lane & 3) * 8;
    jstride = 16 * rs;
    ldsbase = (wave * 32) * 32; ldsstep = 16 * 32;
    nissue = 2; kadv = 32;
  }

  // A-direct per-lane base: row (wm+lr), chunk lg (hi at +0, lo at +8 u16).
  const u16* AD = nullptr;
  if (ADIR) AD = gA + (long)(wm + lr) * rs + lg * 16;

  f32x4 acc[4][4] = {};

  for (int k0 = 0; k0 < K; k0 += BK){
    __syncthreads();
    B8 ah[4], al[4];
    if constexpr (ADIR){
      #pragma unroll 4
      for (int j = 0; j < 4; j++)
        gload16(pb + j * jstride, &lds1[ldsbase + j * ldsstep]);
      pb += kadv;
      // A fragments straight from global (L2-resident); issued pre-barrier so
      // latency overlaps the staging drain.
      const u16* pk = AD + (long)k0 * 2;
      #pragma unroll
      for (int mt = 0; mt < 4; mt++){
        const u16* p = pk + (long)(mt * 16) * rs;
        ah[mt].u = *(const u16x8*)p;
        al[mt].u = *(const u16x8*)(p + 8);
      }
    } else {
      #pragma unroll 4
      for (int j = 0; j < nissue; j++){
        gload16(pa + j * jstride, &lds0[ldsbase + j * ldsstep]);
        gload16(pb + j * jstride, &lds1[ldsbase + j * ldsstep]);
      }
      pa += kadv; pb += kadv;
    }
    __syncthreads();

    if (DUAL){
      B8 bh[4], bl[4];
      if constexpr (!ADIR){
        #pragma unroll
        for (int mt = 0; mt < 4; mt++){
          int row = wm + mt * 16 + lr;
          ah[mt].u = *(const u16x8*)&lds0[lds2_idx(row, lg * 2)];
          al[mt].u = *(const u16x8*)&lds0[lds2_idx(row, lg * 2 + 1)];
        }
      }
      #pragma unroll
      for (int nt = 0; nt < 4; nt++){
        int row = wn + nt * 16 + lr;
        bh[nt].u = *(const u16x8*)&lds1[lds2_idx(row, lg * 2)];
        bl[nt].u = *(const u16x8*)&lds1[lds2_idx(row, lg * 2 + 1)];
      }
      #pragma unroll
      for (int mt = 0; mt < 4; mt++){
        #pragma unroll
        for (int nt = 0; nt < 4; nt++){
          acc[mt][nt] = __builtin_amdgcn_mfma_f32_16x16x32_bf16(ah[mt].b, bh[nt].b, acc[mt][nt], 0, 0, 0);
          acc[mt][nt] = __builtin_amdgcn_mfma_f32_16x16x32_bf16(ah[mt].b, bl[nt].b, acc[mt][nt], 0, 0, 0);
          acc[mt][nt] = __builtin_amdgcn_mfma_f32_16x16x32_bf16(al[mt].b, bh[nt].b, acc[mt][nt], 0, 0, 0);
        }
      }
    } else {
      B8 af[4], bf[4];
      #pragma unroll
      for (int mt = 0; mt < 4; mt++)
        af[mt].u = *(const u16x8*)&lds0[lds1_idx(wm + mt * 16 + lr, lg)];
      #pragma unroll
      for (int nt = 0; nt < 4; nt++)
        bf[nt].u = *(const u16x8*)&lds1[lds1_idx(wn + nt * 16 + lr, lg)];
      #pragma unroll
      for (int mt = 0; mt < 4; mt++)
        #pragma unroll
        for (int nt = 0; nt < 4; nt++)
          acc[mt][nt] = __builtin_amdgcn_mfma_f32_16x16x32_bf16(af[mt].b, bf[nt].b, acc[mt][nt], 0, 0, 0);
    }
  }

  // epilogue: C/D layout col=lane&15, row=(lane>>4)*4+reg  [m89-verified]
  const int rq = lg * 4;
  #pragma unroll
  for (int nt = 0; nt < 4; nt++){
    const int n = tileN + wn + nt * 16 + lr;
    float bv = 0.f;
    if (EPI == 0 && bias) bv = bias[n];
    if (EPI == 2 && bias) bv = bias[(long)tz * N + n];
    #pragma unroll
    for (int mt = 0; mt < 4; mt++){
      #pragma unroll
      for (int r = 0; r < 4; r++){
        const int m = tileM + wm + mt * 16 + rq + r;
        float val = acc[mt][nt][r] + bv;
        if (EPI == 0){
          u16 h = f2b(val);
          u16* o = (u16*)out0 + (long)tz * sOb + (long)m * 2 * N + ((n >> 3) << 4) + (n & 7);
          o[0] = h;
          o[8] = f2b(val - b2f(h));
        } else if (EPI == 2){
          ((float*)out0)[(long)tz * sOb + (long)m * N + n] = val;
        } else if (EPI == 3){
          float res = residual[(long)tz * sRb + (long)m * N + n];
          ((float*)out0)[(long)tz * sOb + (long)m * N + n] = val + res;
        } else {  // EPI == 4: transposed-coalesced bf16, bias by m
          if (bias) val += bias[m];
          long idx = (long)(n / seq) * ((long)M * seq) + (long)m * seq + (n % seq);
          ((u16*)out0)[idx] = f2b(val);
        }
      }
    }
  }
}

template<bool DUAL, int EPI>
__global__ __launch_bounds__(256, 4)
void gemm_nt(const u16* __restrict__ A, const u16* __restrict__ Bm,
             const float* __restrict__ bias, const float* __restrict__ residual,
             void* __restrict__ out0,
             int M, int N, int K, int Krow,
             long sAb, long sBb, long sOb, long sRb, int seq)
{
  constexpr int RW = DUAL ? 64 : 32;
  __shared__ u16 sh[2 * BM * RW];
  int tx, ty, tz; xcd_remap(tx, ty, tz);
  gemm_nt_body<DUAL, EPI, false>(tx, ty, tz, sh, sh + BM * RW,
                                 A, Bm, bias, residual, out0,
                                 M, N, K, Krow, sAb, sBb, sOb, sRb, seq);
}

// ADIR dual GEMM for step 8: B staged in LDS (16 KB), A direct from L2.
// (256,3): unified VGPR+AGPR budget 170/wave (acc 64 + frags 64 + addressing).
// 3 blocks/CU = 12 waves/CU.
__global__ __launch_bounds__(256, 3)
void gemm_nt_adir(const u16* __restrict__ A, const u16* __restrict__ Bm,
                  const float* __restrict__ bias, float* __restrict__ out,
                  int M, int N, int K, int Krow,
                  long sAb, long sBb, long sOb)
{
  __shared__ u16 sh[BM * 64];   // B panel only
  int tx, ty, tz; xcd_remap(tx, ty, tz);
  gemm_nt_body<true, 2, true>(tx, ty, tz, nullptr, sh,
                              A, Bm, bias, nullptr, out,
                              M, N, K, Krow, sAb, sBb, sOb, 0, 0);
}

// ---------------- fused steps 3+7: two independent 512-block GEMMs ----------------
// Each alone fills only 2 blocks/CU; fused 1024-block launch co-resides both at 4/CU.
__global__ __launch_bounds__(256, 4)
void gemm_step37(const u16* __restrict__ Wv_b, const u16* __restrict__ v_b,
                 const float* __restrict__ bv, u16* __restrict__ vpT,
                 const u16* __restrict__ q_pair, const u16* __restrict__ Mt_pair,
                 u16* __restrict__ tmp_pair)
{
  __shared__ u16 sh[2 * BM * 64];   // 32 KB: dual needs full, single uses half-stride
  const int b = blockIdx.x, xcd = b & 7, i = b >> 3;
  if (i < 64){
    // step 3: vpT = Wv_b @ v_b^T + bv, EPI4, grid was (64, 8): tx = rank&63, ty = rank>>6
    const int rank = xcd * 64 + i;
    gemm_nt_body<false, 4, false>(rank & 63, rank >> 6, 0, sh, sh + BM * 32,
                                  Wv_b, v_b, bv, nullptr, vpT,
                                  1024, 8192, 1024, 1024, 0, 0, 0, 0, 2048);
  } else {
    // step 7: tmp_pair = q_pair @ Mt_pair^T, EPI0, grid was (8, 64): tx = rank&7, ty = rank>>3
    const int rank = xcd * 64 + (i - 64);
    gemm_nt_body<true, 0, false>(rank & 7, rank >> 3, 0, sh, sh + BM * 64,
                                 q_pair, Mt_pair, nullptr, nullptr, tmp_pair,
                                 8192, 1024, 1024, 1024, 0, 0, 0, 0, 2048);
  }
}

// ---------------- row softmax: fp32 scores -> bf16 probs (n == 2048) ----------------
__global__ __launch_bounds__(256)
void softmax_kernel(const float* __restrict__ S, u16* __restrict__ P, int n){
  const long row = blockIdx.x;
  const float* r = S + row * (long)n;
  const int t = threadIdx.x;
  float v[8];
  float mx = -3.0e38f;
  #pragma unroll
  for (int i = 0; i < 8; i++){ v[i] = r[t + (i << 8)]; mx = fmaxf(mx, v[i]); }
  #pragma unroll
  for (int off = 32; off > 0; off >>= 1) mx = fmaxf(mx, __shfl_xor(mx, off, 64));
  __shared__ float red[8];
  const int wave = t >> 6;
  if ((t & 63) == 0) red[wave] = mx;
  __syncthreads();
  mx = fmaxf(fmaxf(red[0], red[1]), fmaxf(red[2], red[3]));
  float s = 0.f;
  #pragma unroll
  for (int i = 0; i < 8; i++){ v[i] = __expf(v[i] - mx); s += v[i]; }
  #pragma unroll
  for (int off = 32; off > 0; off >>= 1) s += __shfl_xor(s, off, 64);
  if ((t & 63) == 0) red[4 + wave] = s;
  __syncthreads();
  s = red[4] + red[5] + red[6] + red[7];
  const float inv = 1.f / s;
  u16* pr = P + row * (long)n;
  #pragma unroll
  for (int i = 0; i < 8; i++) pr[t + (i << 8)] = f2b(v[i] * inv);
}

extern "C" void kernel_launch(void* const* d_in, const int* in_sizes, int n_in,
                              void* d_out, int out_size, void* d_ws, size_t ws_size,
                              hipStream_t stream){
  (void)in_sizes; (void)n_in; (void)out_size; (void)ws_size;
  const float* q  = (const float*)d_in[0];
  const float* k  = (const float*)d_in[1];
  const float* v  = (const float*)d_in[2];
  const float* Wq = (const float*)d_in[3];
  const float* bq = (const float*)d_in[4];
  const float* Wk = (const float*)d_in[5];
  // bk enters only a row-constant term: softmax-invariant, dropped
  const float* Wv = (const float*)d_in[7];
  const float* bv = (const float*)d_in[8];
  float* out = (float*)d_out;

  const int B = 4, S = 2048, F = 1024;
  const long NSF = (long)B * S * F;   // 8 Mi
  const long NFF = (long)F * F;       // 1 Mi
  const long NSS = (long)B * S * S;   // 16 Mi

  char* w = (char*)d_ws;
  auto alloc = [&](long bytes) -> char* {
    char* p = w; w += (bytes + 255) & ~(long)255; return p;
  };
  // persistent
  u16*   tmp_pair = (u16*)alloc(2 * NSF * 2);   // (q M^T) dual pair, 33.5 MB
  u16*   k_pair   = (u16*)alloc(2 * NSF * 2);   // raw k dual pair,   33.5 MB
  u16*   vpT      = (u16*)alloc(NSF * 2);       // 16.8 MB
  float* kb       = (float*)alloc((long)B * S * 4);
  // zone2 (100.7 MB): scores+attn alias the phase-1 temporaries
  char* zone2 = alloc(NSS * 2 + NSS * 4);
  u16*   attn   = (u16*)zone2;
  float* scores = (float*)(zone2 + NSS * 2);
  // phase-1 occupants (dead before their aliasing writer runs):
  u16*   q_pair   = (u16*)zone2;                        // == attn region
  char*  z3       = zone2 + NSS * 2;                    // == scores region
  u16*   v_b      = (u16*)z3;                           // 16.8 MB
  u16*   Wv_b     = (u16*)(z3 + NSF * 2);               // 2.1 MB
  u16*   WqT_pair = (u16*)(z3 + NSF * 2 + NFF * 2);     // 4.2 MB
  u16*   WkT_pair = WqT_pair + 2 * NFF;                 // 4.2 MB
  float* b_vec    = (float*)(WkT_pair + 2 * NFF);       // 4 KB
  float* Mt_part  = (float*)((char*)b_vec + 4096);      // 4 x 4.2 MB
  u16*   Mt_pair  = (u16*)((char*)Mt_part + 4 * NFF * 4);

  dim3 blk(256);

  // 1) prep: v/Wv split, Wq/Wk transpose+dual-split
  prep_kernel<<<dim3(5120), blk, 0, stream>>>(
      v, Wv, Wq, Wk, v_b, Wv_b, WqT_pair, WkT_pair);

  // 2) b = Wk^T bq (parallel, from WkT_pair hi+lo)
  bvec_kernel<<<dim3(256), blk, 0, stream>>>(WkT_pair, bq, b_vec);

  // 4) split q,k (dual) + kb[row] = k_row . b
  split_qk_kernel<<<dim3(8192), blk, 0, stream>>>(q, k, b_vec, q_pair, k_pair, kb);

  // 5) Mt partials: Mt[e,f] = sum_g Wk[g,e]Wq[g,f], K split 4x256
  gemm_nt<true, 2><<<dim3(F / BN, F / BM, 4), blk, 0, stream>>>(
      WkT_pair, WqT_pair, nullptr, nullptr, Mt_part,
      F, F, 256, F, 512, 512, NFF, 0, S);

  // 6) Mt_pair = dual-split(sum of partials)
  reduce_split_kernel<<<dim3(512), blk, 0, stream>>>(Mt_part, Mt_pair, NFF);

  // 3+7 fused) vpT = Wv v^T + bv  AND  tmp = q @ Mt^T (co-resident 4 blocks/CU)
  gemm_step37<<<dim3(1024), blk, 0, stream>>>(
      Wv_b, v_b, bv, vpT, q_pair, Mt_pair, tmp_pair);

  // 8) scores[z] = tmp[z] @ k[z]^T + kb[z][:]  (fp32) — ADIR: A direct from L2
  gemm_nt_adir<<<dim3(S / BN, S / BM, B), blk, 0, stream>>>(
      tmp_pair, k_pair, kb, scores,
      S, S, F, F, (long)S * 2 * F, (long)S * 2 * F, (long)S * S);

  // 9) attn = softmax(scores) (bf16)
  softmax_kernel<<<dim3(B * S), blk, 0, stream>>>(scores, attn, S);

  // 10) out[z] = attn[z] @ vp[z] + q[z]
  gemm_nt<false, 3><<<dim3(F / BN, S / BM, B), blk, 0, stream>>>(
      attn, vpT, nullptr, q, out,
      S, F, S, S, (long)S * S, (long)F * S, (long)S * F, (long)S * F, S);
}

// Round 6
// 455.503 us; speedup vs baseline: 1.0526x; 1.0526x over previous
//
#include <hip/hip_runtime.h>

typedef unsigned short u16;
typedef __bf16 bf16x8 __attribute__((ext_vector_type(8)));
typedef float f32x4 __attribute__((ext_vector_type(4)));
typedef u16 u16x8 __attribute__((ext_vector_type(8)));

union B8 { u16x8 u; bf16x8 b; };

__device__ __forceinline__ u16 f2b(float f){
  unsigned u = __float_as_uint(f);
  return (u16)((u + 0x7FFFu + ((u >> 16) & 1u)) >> 16);
}
__device__ __forceinline__ float b2f(u16 h){ return __uint_as_float(((unsigned)h) << 16); }

__device__ __forceinline__ void gload16(const u16* g, u16* l){
  __builtin_amdgcn_global_load_lds((const __attribute__((address_space(1))) void*)g,
                                   (__attribute__((address_space(3))) void*)l, 16, 0, 0);
}

// ---------------- prep kernel (+ fused bvec) ----------------
// blocks: [0,4) b_vec = Wk^T bq direct from fp32 Wk (coalesced column reads) |
//         [4,4100) v->v_b single | [4100,4612) Wv->Wv_b single |
//         [4612,5124) transpose+dual-split Wq->WqT_pair, Wk->WkT_pair
__global__ __launch_bounds__(256) void prep_kernel(
    const float* __restrict__ v, const float* __restrict__ Wv,
    const float* __restrict__ Wq, const float* __restrict__ Wk,
    const float* __restrict__ bq,
    u16* __restrict__ v_b, u16* __restrict__ Wv_b,
    u16* __restrict__ WqT_pair, u16* __restrict__ WkT_pair,
    float* __restrict__ b_vec)
{
  __shared__ float lds[64][65];
  const int blk = blockIdx.x, t = threadIdx.x;
  if (blk < 4){
    // b[e] = sum_g Wk[g][e] * bq[g]; lane e coalesced across the wave
    const int e = blk * 256 + t;
    float acc = 0.f;
    #pragma unroll 8
    for (int g = 0; g < 1024; g++)
      acc += Wk[(long)g * 1024 + e] * bq[g];
    b_vec[e] = acc;
    return;
  }
  const int b2 = blk - 4;
  if (b2 < 4608){
    const float* src; u16* dst; long base;
    if (b2 < 4096){ src = v;  dst = v_b;  base = b2; }
    else          { src = Wv; dst = Wv_b; base = b2 - 4096; }
    long i = base * 256 + t;
    float4 x0 = ((const float4*)src)[2 * i];
    float4 x1 = ((const float4*)src)[2 * i + 1];
    float xs[8] = {x0.x, x0.y, x0.z, x0.w, x1.x, x1.y, x1.z, x1.w};
    u16x8 h;
    #pragma unroll
    for (int j = 0; j < 8; j++) h[j] = f2b(xs[j]);
    ((u16x8*)dst)[i] = h;
  } else {
    int tt = b2 - 4608;
    const float* W = (tt >> 8) ? Wk : Wq;
    u16* outp      = (tt >> 8) ? WkT_pair : WqT_pair;
    int t16 = tt & 255, g0 = (t16 >> 4) * 64, f0 = (t16 & 15) * 64;
    int c4 = (t & 15) * 4, r0 = t >> 4;
    #pragma unroll
    for (int it = 0; it < 4; it++){
      int r = r0 + it * 16;
      float4 x = *(const float4*)&W[(long)(g0 + r) * 1024 + f0 + c4];
      lds[r][c4] = x.x; lds[r][c4+1] = x.y; lds[r][c4+2] = x.z; lds[r][c4+3] = x.w;
    }
    __syncthreads();
    #pragma unroll
    for (int it = 0; it < 2; it++){
      int task = t + it * 256;           // 512 tasks = 64 f-rows x 8 g-groups
      int fl = task >> 3, gi = task & 7;
      u16x8 h, l;
      #pragma unroll
      for (int jj = 0; jj < 8; jj++){
        float xv = lds[gi * 8 + jj][fl];
        h[jj] = f2b(xv); l[jj] = f2b(xv - b2f(h[jj]));
      }
      u16* o = outp + (long)(f0 + fl) * 2048 + ((g0 >> 3) + gi) * 16;
      *(u16x8*)o = h;
      *(u16x8*)(o + 8) = l;
    }
  }
}

// ---------------- reduce 4 fp32 partials -> dual pair ----------------
__global__ __launch_bounds__(256) void reduce_split_kernel(
    const float* __restrict__ part, u16* __restrict__ out_pair, long nper)
{
  long i = (long)blockIdx.x * 256 + threadIdx.x;   // 8-elem group index
  float s[8];
  #pragma unroll
  for (int j = 0; j < 8; j++) s[j] = 0.f;
  #pragma unroll
  for (int z = 0; z < 4; z++){
    float4 a0 = ((const float4*)(part + z * nper))[2 * i];
    float4 a1 = ((const float4*)(part + z * nper))[2 * i + 1];
    s[0]+=a0.x; s[1]+=a0.y; s[2]+=a0.z; s[3]+=a0.w;
    s[4]+=a1.x; s[5]+=a1.y; s[6]+=a1.z; s[7]+=a1.w;
  }
  u16x8 h, l;
  #pragma unroll
  for (int j = 0; j < 8; j++){ h[j] = f2b(s[j]); l[j] = f2b(s[j] - b2f(h[j])); }
  long e = (i * 8) >> 10;
  long g = i & 127;
  u16* o = out_pair + e * 2048 + g * 16;
  *(u16x8*)o = h;
  *(u16x8*)(o + 8) = l;
}

// ---------------- XCD-aware block remap (verified R3: FETCH 368->71 MB) ----------------
__device__ __forceinline__ void xcd_remap(int& tx, int& ty, int& tz){
  const int GX = gridDim.x, GY = gridDim.y;
  int b  = blockIdx.x + GX * (blockIdx.y + GY * blockIdx.z);
  int NB = GX * GY * gridDim.z;
  int rank = (b & 7) * (NB >> 3) + (b >> 3);
  int pz = GX * GY;
  tz = rank / pz;
  int r = rank - tz * pz;
  ty = r / GX;
  tx = r - ty * GX;
}

// ---------------- NT GEMM body: C[m][n] = sum_k A[m][k] * B[n][k] ----------------
// EPI: 0 = +bias[n] (nullable), write paired hi|lo (batched by sOb)
//      2 = (+ per-(z,n) col bias if non-null) write fp32 C (batched by sOb)
//      3 = + residual, write fp32 C (batched)
//      4 = +bias[m], write bf16 batch-transposed: out[(n/seq)][m][n%seq] (coalesced in n)
constexpr int BM = 128, BN = 128, BK = 32;

__device__ __forceinline__ int lds1_idx(int row, int g){ return row * 32 + g * 8; }
__device__ __forceinline__ int lds2_idx(int row, int g){
  return row * 64 + (((g ^ (row & 7)) & 7) << 3);
}

// NOTE: 4 blocks/CU. R6's (256,8) capped the unified VGPR+AGPR budget at 64/wave ->
// acc[4][4] spilled to scratch. Do not raise. R2/R3: 256^2 1-block/CU pipelined
// variants measured 101/95 us vs this structure's 90 us. R5: A-direct-from-global
// (no LDS for A) measured 160 us — per-lane frag loads are uncoalesced 16B x 64
// scattered requests (FETCH +20MB, VALUBusy 9.6%). LDS staging IS the coalescer;
// keep 128^2 staged, 4 blocks/CU.
template<bool DUAL, int EPI>
__device__ __forceinline__ void gemm_nt_body(
    int tx, int ty, int tz, u16* __restrict__ lds0, u16* __restrict__ lds1,
    const u16* __restrict__ A, const u16* __restrict__ Bm,
    const float* __restrict__ bias, const float* __restrict__ residual,
    void* __restrict__ out0,
    int M, int N, int K, int Krow,
    long sAb, long sBb, long sOb, long sRb, int seq)
{
  const int t = threadIdx.x;
  const int tileM = ty * BM;
  const int tileN = tx * BN;
  const long rs = DUAL ? 2L * Krow : (long)Krow;

  const u16* gA = A  + tz * sAb + (long)tileM * rs;
  const u16* gB = Bm + tz * sBb + (long)tileN * rs;

  const int wave = t >> 6, lane = t & 63;
  const int wm = (wave >> 1) * 64, wn = (wave & 1) * 64;
  const int lr = lane & 15;
  const int lg = lane >> 4;

  const u16 *pa, *pb;
  long jstride;
  int  ldsbase, ldsstep, nissue, kadv;
  if (DUAL){
    const int lr8 = lane >> 3, sl = lane & 7;
    const int g = sl ^ lr8;
    pa = gA + (long)(wave * 32 + lr8) * rs + g * 8;
    pb = gB + (long)(wave * 32 + lr8) * rs + g * 8;
    jstride = 8 * rs;
    ldsbase = (wave * 32) * 64; ldsstep = 8 * 64;
    nissue = 4; kadv = 64;
  } else {
    pa = gA + (long)(wave * 32 + (lane >> 2)) * rs + (lane & 3) * 8;
    pb = gB + (long)(wave * 32 + (lane >> 2)) * rs + (lane & 3) * 8;
    jstride = 16 * rs;
    ldsbase = (wave * 32) * 32; ldsstep = 16 * 32;
    nissue = 2; kadv = 32;
  }

  f32x4 acc[4][4] = {};

  for (int k0 = 0; k0 < K; k0 += BK){
    __syncthreads();
    #pragma unroll 4
    for (int j = 0; j < nissue; j++){
      gload16(pa + j * jstride, &lds0[ldsbase + j * ldsstep]);
      gload16(pb + j * jstride, &lds1[ldsbase + j * ldsstep]);
    }
    pa += kadv; pb += kadv;
    __syncthreads();

    if (DUAL){
      B8 ah[4], al[4], bh[4], bl[4];
      #pragma unroll
      for (int mt = 0; mt < 4; mt++){
        int row = wm + mt * 16 + lr;
        ah[mt].u = *(const u16x8*)&lds0[lds2_idx(row, lg * 2)];
        al[mt].u = *(const u16x8*)&lds0[lds2_idx(row, lg * 2 + 1)];
      }
      #pragma unroll
      for (int nt = 0; nt < 4; nt++){
        int row = wn + nt * 16 + lr;
        bh[nt].u = *(const u16x8*)&lds1[lds2_idx(row, lg * 2)];
        bl[nt].u = *(const u16x8*)&lds1[lds2_idx(row, lg * 2 + 1)];
      }
      #pragma unroll
      for (int mt = 0; mt < 4; mt++){
        #pragma unroll
        for (int nt = 0; nt < 4; nt++){
          acc[mt][nt] = __builtin_amdgcn_mfma_f32_16x16x32_bf16(ah[mt].b, bh[nt].b, acc[mt][nt], 0, 0, 0);
          acc[mt][nt] = __builtin_amdgcn_mfma_f32_16x16x32_bf16(ah[mt].b, bl[nt].b, acc[mt][nt], 0, 0, 0);
          acc[mt][nt] = __builtin_amdgcn_mfma_f32_16x16x32_bf16(al[mt].b, bh[nt].b, acc[mt][nt], 0, 0, 0);
        }
      }
    } else {
      B8 af[4], bf[4];
      #pragma unroll
      for (int mt = 0; mt < 4; mt++)
        af[mt].u = *(const u16x8*)&lds0[lds1_idx(wm + mt * 16 + lr, lg)];
      #pragma unroll
      for (int nt = 0; nt < 4; nt++)
        bf[nt].u = *(const u16x8*)&lds1[lds1_idx(wn + nt * 16 + lr, lg)];
      #pragma unroll
      for (int mt = 0; mt < 4; mt++)
        #pragma unroll
        for (int nt = 0; nt < 4; nt++)
          acc[mt][nt] = __builtin_amdgcn_mfma_f32_16x16x32_bf16(af[mt].b, bf[nt].b, acc[mt][nt], 0, 0, 0);
    }
  }

  // epilogue: C/D layout col=lane&15, row=(lane>>4)*4+reg  [m89-verified]
  const int rq = lg * 4;
  #pragma unroll
  for (int nt = 0; nt < 4; nt++){
    const int n = tileN + wn + nt * 16 + lr;
    float bv = 0.f;
    if (EPI == 0 && bias) bv = bias[n];
    if (EPI == 2 && bias) bv = bias[(long)tz * N + n];
    #pragma unroll
    for (int mt = 0; mt < 4; mt++){
      #pragma unroll
      for (int r = 0; r < 4; r++){
        const int m = tileM + wm + mt * 16 + rq + r;
        float val = acc[mt][nt][r] + bv;
        if (EPI == 0){
          u16 h = f2b(val);
          u16* o = (u16*)out0 + (long)tz * sOb + (long)m * 2 * N + ((n >> 3) << 4) + (n & 7);
          o[0] = h;
          o[8] = f2b(val - b2f(h));
        } else if (EPI == 2){
          ((float*)out0)[(long)tz * sOb + (long)m * N + n] = val;
        } else if (EPI == 3){
          float res = residual[(long)tz * sRb + (long)m * N + n];
          ((float*)out0)[(long)tz * sOb + (long)m * N + n] = val + res;
        } else {  // EPI == 4: transposed-coalesced bf16, bias by m
          if (bias) val += bias[m];
          long idx = (long)(n / seq) * ((long)M * seq) + (long)m * seq + (n % seq);
          ((u16*)out0)[idx] = f2b(val);
        }
      }
    }
  }
}

template<bool DUAL, int EPI>
__global__ __launch_bounds__(256, 4)
void gemm_nt(const u16* __restrict__ A, const u16* __restrict__ Bm,
             const float* __restrict__ bias, const float* __restrict__ residual,
             void* __restrict__ out0,
             int M, int N, int K, int Krow,
             long sAb, long sBb, long sOb, long sRb, int seq)
{
  constexpr int RW = DUAL ? 64 : 32;
  __shared__ u16 sh[2 * BM * RW];
  int tx, ty, tz; xcd_remap(tx, ty, tz);
  gemm_nt_body<DUAL, EPI>(tx, ty, tz, sh, sh + BM * RW,
                          A, Bm, bias, residual, out0,
                          M, N, K, Krow, sAb, sBb, sOb, sRb, seq);
}

// ---------------- fused: step 5 (256-block GEMM, 1 block/CU alone) + split_qk ------
// step 5 is compute-bound at 1 block/CU; split_qk is memory-bound with 8192 blocks.
// Independent after prep -> co-schedule in one 8448-block launch: GEMM blocks first,
// split blocks fill the remaining CU slots and hide step 5 entirely.
__global__ __launch_bounds__(256, 4)
void fused_s5_qk(const u16* __restrict__ WkT_pair, const u16* __restrict__ WqT_pair,
                 float* __restrict__ Mt_part,
                 const float* __restrict__ q, const float* __restrict__ kk,
                 const float* __restrict__ b,
                 u16* __restrict__ q_pair, u16* __restrict__ k_pair,
                 float* __restrict__ kb)
{
  __shared__ u16 sh[2 * BM * 64];   // 32 KB (gemm path); split path aliases 16 B
  const int blk = blockIdx.x, t = threadIdx.x;
  if (blk < 256){
    // step 5: Mt partials, K split 4x256 — exact replica of grid (8,8,4) + xcd_remap
    const int rank = (blk & 7) * 32 + (blk >> 3);
    const int tz = rank >> 6, rem = rank & 63;
    gemm_nt_body<true, 2>(rem & 7, rem >> 3, tz, sh, sh + BM * 64,
                          WkT_pair, WqT_pair, nullptr, nullptr, Mt_part,
                          1024, 1024, 256, 1024, 512, 512, 1024L * 1024, 0, 2048);
    return;
  }
  // split q,k (dual paired) + kb[row] = k_row . b
  const int sblk = blk - 256;
  const bool isK = sblk >= 4096;
  const float* src = isK ? kk : q;
  u16* dst = isK ? k_pair : q_pair;
  long base = isK ? sblk - 4096 : sblk;
  long i = base * 256 + t;
  float4 x0 = ((const float4*)src)[2 * i];
  float4 x1 = ((const float4*)src)[2 * i + 1];
  float xs[8] = {x0.x, x0.y, x0.z, x0.w, x1.x, x1.y, x1.z, x1.w};
  u16x8 h, l;
  #pragma unroll
  for (int j = 0; j < 8; j++){ h[j] = f2b(xs[j]); l[j] = f2b(xs[j] - b2f(h[j])); }
  ((u16x8*)dst)[2 * i]     = h;
  ((u16x8*)dst)[2 * i + 1] = l;
  if (isK){
    const int f = (t & 127) * 8;
    float d = 0.f;
    #pragma unroll
    for (int j = 0; j < 8; j++) d += xs[j] * b[f + j];
    #pragma unroll
    for (int off = 32; off > 0; off >>= 1) d += __shfl_xor(d, off, 64);
    float* red = (float*)sh;
    if ((t & 63) == 0) red[t >> 6] = d;
    __syncthreads();
    if (t == 0)   kb[base * 2]     = red[0] + red[1];
    if (t == 128) kb[base * 2 + 1] = red[2] + red[3];
  }
}

// ---------------- fused steps 3+7: two independent 512-block GEMMs ----------------
// Each alone fills only 2 blocks/CU; fused 1024-block launch co-resides both at 4/CU.
__global__ __launch_bounds__(256, 4)
void gemm_step37(const u16* __restrict__ Wv_b, const u16* __restrict__ v_b,
                 const float* __restrict__ bv, u16* __restrict__ vpT,
                 const u16* __restrict__ q_pair, const u16* __restrict__ Mt_pair,
                 u16* __restrict__ tmp_pair)
{
  __shared__ u16 sh[2 * BM * 64];   // 32 KB: dual needs full, single uses half-stride
  const int b = blockIdx.x, xcd = b & 7, i = b >> 3;
  if (i < 64){
    // step 3: vpT = Wv_b @ v_b^T + bv, EPI4, grid was (64, 8): tx = rank&63, ty = rank>>6
    const int rank = xcd * 64 + i;
    gemm_nt_body<false, 4>(rank & 63, rank >> 6, 0, sh, sh + BM * 32,
                           Wv_b, v_b, bv, nullptr, vpT,
                           1024, 8192, 1024, 1024, 0, 0, 0, 0, 2048);
  } else {
    // step 7: tmp_pair = q_pair @ Mt_pair^T, EPI0, grid was (8, 64): tx = rank&7, ty = rank>>3
    const int rank = xcd * 64 + (i - 64);
    gemm_nt_body<true, 0>(rank & 7, rank >> 3, 0, sh, sh + BM * 64,
                          q_pair, Mt_pair, nullptr, nullptr, tmp_pair,
                          8192, 1024, 1024, 1024, 0, 0, 0, 0, 2048);
  }
}

// ---------------- row softmax: fp32 scores -> bf16 probs (n == 2048) ----------------
__global__ __launch_bounds__(256)
void softmax_kernel(const float* __restrict__ S, u16* __restrict__ P, int n){
  const long row = blockIdx.x;
  const float* r = S + row * (long)n;
  const int t = threadIdx.x;
  float v[8];
  float mx = -3.0e38f;
  #pragma unroll
  for (int i = 0; i < 8; i++){ v[i] = r[t + (i << 8)]; mx = fmaxf(mx, v[i]); }
  #pragma unroll
  for (int off = 32; off > 0; off >>= 1) mx = fmaxf(mx, __shfl_xor(mx, off, 64));
  __shared__ float red[8];
  const int wave = t >> 6;
  if ((t & 63) == 0) red[wave] = mx;
  __syncthreads();
  mx = fmaxf(fmaxf(red[0], red[1]), fmaxf(red[2], red[3]));
  float s = 0.f;
  #pragma unroll
  for (int i = 0; i < 8; i++){ v[i] = __expf(v[i] - mx); s += v[i]; }
  #pragma unroll
  for (int off = 32; off > 0; off >>= 1) s += __shfl_xor(s, off, 64);
  if ((t & 63) == 0) red[4 + wave] = s;
  __syncthreads();
  s = red[4] + red[5] + red[6] + red[7];
  const float inv = 1.f / s;
  u16* pr = P + row * (long)n;
  #pragma unroll
  for (int i = 0; i < 8; i++) pr[t + (i << 8)] = f2b(v[i] * inv);
}

extern "C" void kernel_launch(void* const* d_in, const int* in_sizes, int n_in,
                              void* d_out, int out_size, void* d_ws, size_t ws_size,
                              hipStream_t stream){
  (void)in_sizes; (void)n_in; (void)out_size; (void)ws_size;
  const float* q  = (const float*)d_in[0];
  const float* k  = (const float*)d_in[1];
  const float* v  = (const float*)d_in[2];
  const float* Wq = (const float*)d_in[3];
  const float* bq = (const float*)d_in[4];
  const float* Wk = (const float*)d_in[5];
  // bk enters only a row-constant term: softmax-invariant, dropped
  const float* Wv = (const float*)d_in[7];
  const float* bv = (const float*)d_in[8];
  float* out = (float*)d_out;

  const int B = 4, S = 2048, F = 1024;
  const long NSF = (long)B * S * F;   // 8 Mi
  const long NFF = (long)F * F;       // 1 Mi
  const long NSS = (long)B * S * S;   // 16 Mi

  char* w = (char*)d_ws;
  auto alloc = [&](long bytes) -> char* {
    char* p = w; w += (bytes + 255) & ~(long)255; return p;
  };
  // persistent
  u16*   tmp_pair = (u16*)alloc(2 * NSF * 2);   // (q M^T) dual pair, 33.5 MB
  u16*   k_pair   = (u16*)alloc(2 * NSF * 2);   // raw k dual pair,   33.5 MB
  u16*   vpT      = (u16*)alloc(NSF * 2);       // 16.8 MB
  float* kb       = (float*)alloc((long)B * S * 4);
  // zone2 (100.7 MB): scores+attn alias the phase-1 temporaries
  char* zone2 = alloc(NSS * 2 + NSS * 4);
  u16*   attn   = (u16*)zone2;
  float* scores = (float*)(zone2 + NSS * 2);
  // phase-1 occupants (dead before their aliasing writer runs):
  u16*   q_pair   = (u16*)zone2;                        // == attn region
  char*  z3       = zone2 + NSS * 2;                    // == scores region
  u16*   v_b      = (u16*)z3;                           // 16.8 MB
  u16*   Wv_b     = (u16*)(z3 + NSF * 2);               // 2.1 MB
  u16*   WqT_pair = (u16*)(z3 + NSF * 2 + NFF * 2);     // 4.2 MB
  u16*   WkT_pair = WqT_pair + 2 * NFF;                 // 4.2 MB
  float* b_vec    = (float*)(WkT_pair + 2 * NFF);       // 4 KB
  float* Mt_part  = (float*)((char*)b_vec + 4096);      // 4 x 4.2 MB
  u16*   Mt_pair  = (u16*)((char*)Mt_part + 4 * NFF * 4);

  dim3 blk(256);

  // 1) prep: v/Wv split, Wq/Wk transpose+dual-split, b_vec = Wk^T bq (4 blocks)
  prep_kernel<<<dim3(5124), blk, 0, stream>>>(
      v, Wv, Wq, Wk, bq, v_b, Wv_b, WqT_pair, WkT_pair, b_vec);

  // 5+4 fused) Mt partials (256 blocks) + split q,k / kb (8192 blocks)
  fused_s5_qk<<<dim3(8448), blk, 0, stream>>>(
      WkT_pair, WqT_pair, Mt_part, q, k, b_vec, q_pair, k_pair, kb);

  // 6) Mt_pair = dual-split(sum of partials)
  reduce_split_kernel<<<dim3(512), blk, 0, stream>>>(Mt_part, Mt_pair, NFF);

  // 3+7 fused) vpT = Wv v^T + bv  AND  tmp = q @ Mt^T (co-resident 4 blocks/CU)
  gemm_step37<<<dim3(1024), blk, 0, stream>>>(
      Wv_b, v_b, bv, vpT, q_pair, Mt_pair, tmp_pair);

  // 8) scores[z] = tmp[z] @ k[z]^T + kb[z][:]  (fp32) — verified 128^2 4-block/CU
  gemm_nt<true, 2><<<dim3(S / BN, S / BM, B), blk, 0, stream>>>(
      tmp_pair, k_pair, kb, nullptr, scores,
      S, S, F, F, (long)S * 2 * F, (long)S * 2 * F, (long)S * S, 0, S);

  // 9) attn = softmax(scores) (bf16)
  softmax_kernel<<<dim3(B * S), blk, 0, stream>>>(scores, attn, S);

  // 10) out[z] = attn[z] @ vp[z] + q[z]
  gemm_nt<false, 3><<<dim3(F / BN, S / BM, B), blk, 0, stream>>>(
      attn, vpT, nullptr, q, out,
      S, F, S, S, (long)S * S, (long)F * S, (long)S * F, (long)S * F, S);
}

// Round 7
// 415.847 us; speedup vs baseline: 1.1529x; 1.0954x over previous
//
#include <hip/hip_runtime.h>

typedef unsigned short u16;
typedef __bf16 bf16x8 __attribute__((ext_vector_type(8)));
typedef float f32x4 __attribute__((ext_vector_type(4)));
typedef u16 u16x8 __attribute__((ext_vector_type(8)));

union B8 { u16x8 u; bf16x8 b; };

__device__ __forceinline__ u16 f2b(float f){
  unsigned u = __float_as_uint(f);
  return (u16)((u + 0x7FFFu + ((u >> 16) & 1u)) >> 16);
}
__device__ __forceinline__ float b2f(u16 h){ return __uint_as_float(((unsigned)h) << 16); }

__device__ __forceinline__ void gload16(const u16* g, u16* l){
  __builtin_amdgcn_global_load_lds((const __attribute__((address_space(1))) void*)g,
                                   (__attribute__((address_space(3))) void*)l, 16, 0, 0);
}

// ---------------- prep kernel ----------------
// blocks: [0,4096) v->v_b single | [4096,4608) Wv->Wv_b single |
//         [4608,5120) transpose+dual-split Wq->WqT_pair, Wk->WkT_pair
__global__ __launch_bounds__(256) void prep_kernel(
    const float* __restrict__ v, const float* __restrict__ Wv,
    const float* __restrict__ Wq, const float* __restrict__ Wk,
    u16* __restrict__ v_b, u16* __restrict__ Wv_b,
    u16* __restrict__ WqT_pair, u16* __restrict__ WkT_pair)
{
  __shared__ float lds[64][65];
  const int blk = blockIdx.x, t = threadIdx.x;
  if (blk < 4608){
    const float* src; u16* dst; long base;
    if (blk < 4096){ src = v;  dst = v_b;  base = blk; }
    else           { src = Wv; dst = Wv_b; base = blk - 4096; }
    long i = base * 256 + t;
    float4 x0 = ((const float4*)src)[2 * i];
    float4 x1 = ((const float4*)src)[2 * i + 1];
    float xs[8] = {x0.x, x0.y, x0.z, x0.w, x1.x, x1.y, x1.z, x1.w};
    u16x8 h;
    #pragma unroll
    for (int j = 0; j < 8; j++) h[j] = f2b(xs[j]);
    ((u16x8*)dst)[i] = h;
  } else {
    int tt = blk - 4608;
    const float* W = (tt >> 8) ? Wk : Wq;
    u16* outp      = (tt >> 8) ? WkT_pair : WqT_pair;
    int t16 = tt & 255, g0 = (t16 >> 4) * 64, f0 = (t16 & 15) * 64;
    int c4 = (t & 15) * 4, r0 = t >> 4;
    #pragma unroll
    for (int it = 0; it < 4; it++){
      int r = r0 + it * 16;
      float4 x = *(const float4*)&W[(long)(g0 + r) * 1024 + f0 + c4];
      lds[r][c4] = x.x; lds[r][c4+1] = x.y; lds[r][c4+2] = x.z; lds[r][c4+3] = x.w;
    }
    __syncthreads();
    #pragma unroll
    for (int it = 0; it < 2; it++){
      int task = t + it * 256;           // 512 tasks = 64 f-rows x 8 g-groups
      int fl = task >> 3, gi = task & 7;
      u16x8 h, l;
      #pragma unroll
      for (int jj = 0; jj < 8; jj++){
        float xv = lds[gi * 8 + jj][fl];
        h[jj] = f2b(xv); l[jj] = f2b(xv - b2f(h[jj]));
      }
      u16* o = outp + (long)(f0 + fl) * 2048 + ((g0 >> 3) + gi) * 16;
      *(u16x8*)o = h;
      *(u16x8*)(o + 8) = l;
    }
  }
}

// ---------------- b[e] = sum_g Wk[g][e] * bq[g], from WkT_pair (hi+lo = fp32-ish) ----
__global__ __launch_bounds__(256) void bvec_kernel(
    const u16* __restrict__ WkT_pair, const float* __restrict__ bq, float* __restrict__ b)
{
  const int wave = threadIdx.x >> 6, lane = threadIdx.x & 63;
  const int e = blockIdx.x * 4 + wave;
  const u16* row = WkT_pair + (long)e * 2048;
  float acc = 0.f;
  #pragma unroll
  for (int ii = 0; ii < 2; ii++){
    int gi = lane * 2 + ii;            // 8-group index 0..127
    const u16* p = row + gi * 16;
    #pragma unroll
    for (int j = 0; j < 8; j++)
      acc += (b2f(p[j]) + b2f(p[j + 8])) * bq[gi * 8 + j];
  }
  #pragma unroll
  for (int off = 32; off > 0; off >>= 1) acc += __shfl_xor(acc, off, 64);
  if (lane == 0) b[e] = acc;
}

// ---------------- split q,k (dual paired) + kb[row] = k_row . b ----------------
__global__ __launch_bounds__(256) void split_qk_kernel(
    const float* __restrict__ q, const float* __restrict__ kk,
    const float* __restrict__ b,
    u16* __restrict__ q_pair, u16* __restrict__ k_pair, float* __restrict__ kb)
{
  const int blk = blockIdx.x, t = threadIdx.x;
  const bool isK = blk >= 4096;
  const float* src = isK ? kk : q;
  u16* dst = isK ? k_pair : q_pair;
  long base = isK ? blk - 4096 : blk;
  long i = base * 256 + t;
  float4 x0 = ((const float4*)src)[2 * i];
  float4 x1 = ((const float4*)src)[2 * i + 1];
  float xs[8] = {x0.x, x0.y, x0.z, x0.w, x1.x, x1.y, x1.z, x1.w};
  u16x8 h, l;
  #pragma unroll
  for (int j = 0; j < 8; j++){ h[j] = f2b(xs[j]); l[j] = f2b(xs[j] - b2f(h[j])); }
  ((u16x8*)dst)[2 * i]     = h;
  ((u16x8*)dst)[2 * i + 1] = l;
  if (isK){
    const int f = (t & 127) * 8;
    float d = 0.f;
    #pragma unroll
    for (int j = 0; j < 8; j++) d += xs[j] * b[f + j];
    #pragma unroll
    for (int off = 32; off > 0; off >>= 1) d += __shfl_xor(d, off, 64);
    __shared__ float red[4];
    if ((t & 63) == 0) red[t >> 6] = d;
    __syncthreads();
    if (t == 0)   kb[base * 2]     = red[0] + red[1];
    if (t == 128) kb[base * 2 + 1] = red[2] + red[3];
  }
}

// ---------------- reduce 4 fp32 partials -> dual pair ----------------
__global__ __launch_bounds__(256) void reduce_split_kernel(
    const float* __restrict__ part, u16* __restrict__ out_pair, long nper)
{
  long i = (long)blockIdx.x * 256 + threadIdx.x;   // 8-elem group index
  float s[8];
  #pragma unroll
  for (int j = 0; j < 8; j++) s[j] = 0.f;
  #pragma unroll
  for (int z = 0; z < 4; z++){
    float4 a0 = ((const float4*)(part + z * nper))[2 * i];
    float4 a1 = ((const float4*)(part + z * nper))[2 * i + 1];
    s[0]+=a0.x; s[1]+=a0.y; s[2]+=a0.z; s[3]+=a0.w;
    s[4]+=a1.x; s[5]+=a1.y; s[6]+=a1.z; s[7]+=a1.w;
  }
  u16x8 h, l;
  #pragma unroll
  for (int j = 0; j < 8; j++){ h[j] = f2b(s[j]); l[j] = f2b(s[j] - b2f(h[j])); }
  long e = (i * 8) >> 10;
  long g = i & 127;
  u16* o = out_pair + e * 2048 + g * 16;
  *(u16x8*)o = h;
  *(u16x8*)(o + 8) = l;
}

// ---------------- XCD-aware block remap (verified R3: FETCH 368->71 MB) ----------------
__device__ __forceinline__ void xcd_remap(int& tx, int& ty, int& tz){
  const int GX = gridDim.x, GY = gridDim.y;
  int b  = blockIdx.x + GX * (blockIdx.y + GY * blockIdx.z);
  int NB = GX * GY * gridDim.z;
  int rank = (b & 7) * (NB >> 3) + (b >> 3);
  int pz = GX * GY;
  tz = rank / pz;
  int r = rank - tz * pz;
  ty = r / GX;
  tx = r - ty * GX;
}

// ---------------- NT GEMM body: C[m][n] = sum_k A[m][k] * B[n][k] ----------------
// EPI: 0 = +bias[n] (nullable), write paired hi|lo (batched by sOb)
//      2 = (+ per-(z,n) col bias if non-null) write fp32 C (batched by sOb)
//      3 = + residual, write fp32 C (batched)
//      4 = +bias[m], write bf16 batch-transposed: out[(n/seq)][m][n%seq] (coalesced in n)
constexpr int BM = 128, BN = 128, BK = 32;

__device__ __forceinline__ int lds1_idx(int row, int g){ return row * 32 + g * 8; }
__device__ __forceinline__ int lds2_idx(int row, int g){
  return row * 64 + (((g ^ (row & 7)) & 7) << 3);
}

// NOTE: 4 blocks/CU. (256,8) capped unified VGPR+AGPR at 64/wave -> spill. Do not
// raise. R2/R3: 256^2 1-block/CU pipelined variants measured 101/95 us vs 90 here.
// R5: A-direct-from-global measured 160 us (uncoalesced frag loads). R6: fusing the
// memory-bound split into a 32KB-LDS kernel halved its occupancy and regressed.
// Keep 128^2 staged, 4 blocks/CU, launch-level co-scheduling only.
template<bool DUAL, int EPI>
__device__ __forceinline__ void gemm_nt_body(
    int tx, int ty, int tz, u16* __restrict__ lds0, u16* __restrict__ lds1,
    const u16* __restrict__ A, const u16* __restrict__ Bm,
    const float* __restrict__ bias, const float* __restrict__ residual,
    void* __restrict__ out0,
    int M, int N, int K, int Krow,
    long sAb, long sBb, long sOb, long sRb, int seq)
{
  const int t = threadIdx.x;
  const int tileM = ty * BM;
  const int tileN = tx * BN;
  const long rs = DUAL ? 2L * Krow : (long)Krow;

  const u16* gA = A  + tz * sAb + (long)tileM * rs;
  const u16* gB = Bm + tz * sBb + (long)tileN * rs;

  const int wave = t >> 6, lane = t & 63;
  const int wm = (wave >> 1) * 64, wn = (wave & 1) * 64;
  const int lr = lane & 15;
  const int lg = lane >> 4;

  const u16 *pa, *pb;
  long jstride;
  int  ldsbase, ldsstep, nissue, kadv;
  if (DUAL){
    const int lr8 = lane >> 3, sl = lane & 7;
    const int g = sl ^ lr8;
    pa = gA + (long)(wave * 32 + lr8) * rs + g * 8;
    pb = gB + (long)(wave * 32 + lr8) * rs + g * 8;
    jstride = 8 * rs;
    ldsbase = (wave * 32) * 64; ldsstep = 8 * 64;
    nissue = 4; kadv = 64;
  } else {
    pa = gA + (long)(wave * 32 + (lane >> 2)) * rs + (lane & 3) * 8;
    pb = gB + (long)(wave * 32 + (lane >> 2)) * rs + (lane & 3) * 8;
    jstride = 16 * rs;
    ldsbase = (wave * 32) * 32; ldsstep = 16 * 32;
    nissue = 2; kadv = 32;
  }

  f32x4 acc[4][4] = {};

  for (int k0 = 0; k0 < K; k0 += BK){
    __syncthreads();
    #pragma unroll 4
    for (int j = 0; j < nissue; j++){
      gload16(pa + j * jstride, &lds0[ldsbase + j * ldsstep]);
      gload16(pb + j * jstride, &lds1[ldsbase + j * ldsstep]);
    }
    pa += kadv; pb += kadv;
    __syncthreads();

    if (DUAL){
      B8 ah[4], al[4], bh[4], bl[4];
      #pragma unroll
      for (int mt = 0; mt < 4; mt++){
        int row = wm + mt * 16 + lr;
        ah[mt].u = *(const u16x8*)&lds0[lds2_idx(row, lg * 2)];
        al[mt].u = *(const u16x8*)&lds0[lds2_idx(row, lg * 2 + 1)];
      }
      #pragma unroll
      for (int nt = 0; nt < 4; nt++){
        int row = wn + nt * 16 + lr;
        bh[nt].u = *(const u16x8*)&lds1[lds2_idx(row, lg * 2)];
        bl[nt].u = *(const u16x8*)&lds1[lds2_idx(row, lg * 2 + 1)];
      }
      #pragma unroll
      for (int mt = 0; mt < 4; mt++){
        #pragma unroll
        for (int nt = 0; nt < 4; nt++){
          acc[mt][nt] = __builtin_amdgcn_mfma_f32_16x16x32_bf16(ah[mt].b, bh[nt].b, acc[mt][nt], 0, 0, 0);
          acc[mt][nt] = __builtin_amdgcn_mfma_f32_16x16x32_bf16(ah[mt].b, bl[nt].b, acc[mt][nt], 0, 0, 0);
          acc[mt][nt] = __builtin_amdgcn_mfma_f32_16x16x32_bf16(al[mt].b, bh[nt].b, acc[mt][nt], 0, 0, 0);
        }
      }
    } else {
      B8 af[4], bf[4];
      #pragma unroll
      for (int mt = 0; mt < 4; mt++)
        af[mt].u = *(const u16x8*)&lds0[lds1_idx(wm + mt * 16 + lr, lg)];
      #pragma unroll
      for (int nt = 0; nt < 4; nt++)
        bf[nt].u = *(const u16x8*)&lds1[lds1_idx(wn + nt * 16 + lr, lg)];
      #pragma unroll
      for (int mt = 0; mt < 4; mt++)
        #pragma unroll
        for (int nt = 0; nt < 4; nt++)
          acc[mt][nt] = __builtin_amdgcn_mfma_f32_16x16x32_bf16(af[mt].b, bf[nt].b, acc[mt][nt], 0, 0, 0);
    }
  }

  // epilogue: C/D layout col=lane&15, row=(lane>>4)*4+reg  [m89-verified]
  const int rq = lg * 4;
  #pragma unroll
  for (int nt = 0; nt < 4; nt++){
    const int n = tileN + wn + nt * 16 + lr;
    float bv = 0.f;
    if (EPI == 0 && bias) bv = bias[n];
    if (EPI == 2 && bias) bv = bias[(long)tz * N + n];
    #pragma unroll
    for (int mt = 0; mt < 4; mt++){
      #pragma unroll
      for (int r = 0; r < 4; r++){
        const int m = tileM + wm + mt * 16 + rq + r;
        float val = acc[mt][nt][r] + bv;
        if (EPI == 0){
          u16 h = f2b(val);
          u16* o = (u16*)out0 + (long)tz * sOb + (long)m * 2 * N + ((n >> 3) << 4) + (n & 7);
          o[0] = h;
          o[8] = f2b(val - b2f(h));
        } else if (EPI == 2){
          ((float*)out0)[(long)tz * sOb + (long)m * N + n] = val;
        } else if (EPI == 3){
          float res = residual[(long)tz * sRb + (long)m * N + n];
          ((float*)out0)[(long)tz * sOb + (long)m * N + n] = val + res;
        } else {  // EPI == 4: transposed-coalesced bf16, bias by m
          if (bias) val += bias[m];
          long idx = (long)(n / seq) * ((long)M * seq) + (long)m * seq + (n % seq);
          ((u16*)out0)[idx] = f2b(val);
        }
      }
    }
  }
}

template<bool DUAL, int EPI>
__global__ __launch_bounds__(256, 4)
void gemm_nt(const u16* __restrict__ A, const u16* __restrict__ Bm,
             const float* __restrict__ bias, const float* __restrict__ residual,
             void* __restrict__ out0,
             int M, int N, int K, int Krow,
             long sAb, long sBb, long sOb, long sRb, int seq)
{
  constexpr int RW = DUAL ? 64 : 32;
  __shared__ u16 sh[2 * BM * RW];
  int tx, ty, tz; xcd_remap(tx, ty, tz);
  gemm_nt_body<DUAL, EPI>(tx, ty, tz, sh, sh + BM * RW,
                          A, Bm, bias, residual, out0,
                          M, N, K, Krow, sAb, sBb, sOb, sRb, seq);
}

// ---------------- fused steps 3+7: two independent 512-block GEMMs ----------------
// Each alone fills only 2 blocks/CU; fused 1024-block launch co-resides both at 4/CU.
__global__ __launch_bounds__(256, 4)
void gemm_step37(const u16* __restrict__ Wv_b, const u16* __restrict__ v_b,
                 const float* __restrict__ bv, u16* __restrict__ vpT,
                 const u16* __restrict__ q_pair, const u16* __restrict__ Mt_pair,
                 u16* __restrict__ tmp_pair)
{
  __shared__ u16 sh[2 * BM * 64];   // 32 KB: dual needs full, single uses half-stride
  const int b = blockIdx.x, xcd = b & 7, i = b >> 3;
  if (i < 64){
    // step 3: vpT = Wv_b @ v_b^T + bv, EPI4, grid was (64, 8): tx = rank&63, ty = rank>>6
    const int rank = xcd * 64 + i;
    gemm_nt_body<false, 4>(rank & 63, rank >> 6, 0, sh, sh + BM * 32,
                           Wv_b, v_b, bv, nullptr, vpT,
                           1024, 8192, 1024, 1024, 0, 0, 0, 0, 2048);
  } else {
    // step 7: tmp_pair = q_pair @ Mt_pair^T, EPI0, grid was (8, 64): tx = rank&7, ty = rank>>3
    const int rank = xcd * 64 + (i - 64);
    gemm_nt_body<true, 0>(rank & 7, rank >> 3, 0, sh, sh + BM * 64,
                          q_pair, Mt_pair, nullptr, nullptr, tmp_pair,
                          8192, 1024, 1024, 1024, 0, 0, 0, 0, 2048);
  }
}

// ---------------- step 10: 64x128 single GEMM, 4 blocks/CU + chunk swizzle ---------
// out[z][m][n] = sum_k attn[z][m][k] * vpT[z][n][k] + q[z][m][n]
// BM=64 doubles the grid to 1024 blocks (4/CU vs 2/CU for the 128^2 shape).
// Chunk swizzle (store (lane&3)^(row&3) via pre-swizzled global src, read
// lg^(row&3)) cuts the single-path 8-way LDS read conflict to 4-way.
// Per-acc MFMA chain identical to gemm_nt<false,3> -> bitwise-same output.
__global__ __launch_bounds__(256, 4)
void gemm_nt64(const u16* __restrict__ A, const u16* __restrict__ Bm,
               const float* __restrict__ residual, float* __restrict__ out,
               int N, int K, int Krow, long sAb, long sBb, long sOb, long sRb)
{
  __shared__ u16 ldsA[64 * 32];    // 4 KB
  __shared__ u16 ldsB[128 * 32];   // 8 KB

  int tx, ty, tz; xcd_remap(tx, ty, tz);
  const int t = threadIdx.x;
  const int tileM = ty * 64, tileN = tx * 128;
  const long rs = (long)Krow;

  const u16* gA = A  + tz * sAb + (long)tileM * rs;
  const u16* gB = Bm + tz * sBb + (long)tileN * rs;

  const int wave = t >> 6, lane = t & 63;
  const int wm = (wave >> 1) * 32, wn = (wave & 1) * 64;
  const int lr = lane & 15, lg = lane >> 4;

  // staging addressing: row-within-issue = lane>>2, source chunk pre-swizzled
  const int srow = lane >> 2;
  const int schunk = (lane & 3) ^ (srow & 3);
  const u16* pa = gA + (long)(wave * 16 + srow) * rs + schunk * 8;
  const u16* pb = gB + (long)(wave * 32 + srow) * rs + schunk * 8;
  const int ldsbaseA = (wave * 16) * 32;
  const int ldsbaseB = (wave * 32) * 32;

  f32x4 acc[2][4] = {};

  for (int k0 = 0; k0 < K; k0 += 32){
    __syncthreads();
    gload16(pa,           &ldsA[ldsbaseA]);
    gload16(pb,           &ldsB[ldsbaseB]);
    gload16(pb + 16 * rs, &ldsB[ldsbaseB + 16 * 32]);
    pa += 32; pb += 32;
    __syncthreads();

    B8 af[2], bf[4];
    #pragma unroll
    for (int mt = 0; mt < 2; mt++){
      int row = wm + mt * 16 + lr;
      af[mt].u = *(const u16x8*)&ldsA[row * 32 + ((lg ^ (row & 3)) & 3) * 8];
    }
    #pragma unroll
    for (int nt = 0; nt < 4; nt++){
      int row = wn + nt * 16 + lr;
      bf[nt].u = *(const u16x8*)&ldsB[row * 32 + ((lg ^ (row & 3)) & 3) * 8];
    }
    #pragma unroll
    for (int mt = 0; mt < 2; mt++)
      #pragma unroll
      for (int nt = 0; nt < 4; nt++)
        acc[mt][nt] = __builtin_amdgcn_mfma_f32_16x16x32_bf16(af[mt].b, bf[nt].b, acc[mt][nt], 0, 0, 0);
  }

  const int rq = lg * 4;
  #pragma unroll
  for (int nt = 0; nt < 4; nt++){
    const int n = tileN + wn + nt * 16 + lr;
    #pragma unroll
    for (int mt = 0; mt < 2; mt++){
      #pragma unroll
      for (int r = 0; r < 4; r++){
        const int m = tileM + wm + mt * 16 + rq + r;
        float res = residual[(long)tz * sRb + (long)m * N + n];
        out[(long)tz * sOb + (long)m * N + n] = acc[mt][nt][r] + res;
      }
    }
  }
}

// ---------------- row softmax: fp32 scores -> bf16 probs (n == 2048) ----------------
__global__ __launch_bounds__(256)
void softmax_kernel(const float* __restrict__ S, u16* __restrict__ P, int n){
  const long row = blockIdx.x;
  const float* r = S + row * (long)n;
  const int t = threadIdx.x;
  float v[8];
  float mx = -3.0e38f;
  #pragma unroll
  for (int i = 0; i < 8; i++){ v[i] = r[t + (i << 8)]; mx = fmaxf(mx, v[i]); }
  #pragma unroll
  for (int off = 32; off > 0; off >>= 1) mx = fmaxf(mx, __shfl_xor(mx, off, 64));
  __shared__ float red[8];
  const int wave = t >> 6;
  if ((t & 63) == 0) red[wave] = mx;
  __syncthreads();
  mx = fmaxf(fmaxf(red[0], red[1]), fmaxf(red[2], red[3]));
  float s = 0.f;
  #pragma unroll
  for (int i = 0; i < 8; i++){ v[i] = __expf(v[i] - mx); s += v[i]; }
  #pragma unroll
  for (int off = 32; off > 0; off >>= 1) s += __shfl_xor(s, off, 64);
  if ((t & 63) == 0) red[4 + wave] = s;
  __syncthreads();
  s = red[4] + red[5] + red[6] + red[7];
  const float inv = 1.f / s;
  u16* pr = P + row * (long)n;
  #pragma unroll
  for (int i = 0; i < 8; i++) pr[t + (i << 8)] = f2b(v[i] * inv);
}

extern "C" void kernel_launch(void* const* d_in, const int* in_sizes, int n_in,
                              void* d_out, int out_size, void* d_ws, size_t ws_size,
                              hipStream_t stream){
  (void)in_sizes; (void)n_in; (void)out_size; (void)ws_size;
  const float* q  = (const float*)d_in[0];
  const float* k  = (const float*)d_in[1];
  const float* v  = (const float*)d_in[2];
  const float* Wq = (const float*)d_in[3];
  const float* bq = (const float*)d_in[4];
  const float* Wk = (const float*)d_in[5];
  // bk enters only a row-constant term: softmax-invariant, dropped
  const float* Wv = (const float*)d_in[7];
  const float* bv = (const float*)d_in[8];
  float* out = (float*)d_out;

  const int B = 4, S = 2048, F = 1024;
  const long NSF = (long)B * S * F;   // 8 Mi
  const long NFF = (long)F * F;       // 1 Mi
  const long NSS = (long)B * S * S;   // 16 Mi

  char* w = (char*)d_ws;
  auto alloc = [&](long bytes) -> char* {
    char* p = w; w += (bytes + 255) & ~(long)255; return p;
  };
  // persistent
  u16*   tmp_pair = (u16*)alloc(2 * NSF * 2);   // (q M^T) dual pair, 33.5 MB
  u16*   k_pair   = (u16*)alloc(2 * NSF * 2);   // raw k dual pair,   33.5 MB
  u16*   vpT      = (u16*)alloc(NSF * 2);       // 16.8 MB
  float* kb       = (float*)alloc((long)B * S * 4);
  // zone2 (100.7 MB): scores+attn alias the phase-1 temporaries
  char* zone2 = alloc(NSS * 2 + NSS * 4);
  u16*   attn   = (u16*)zone2;
  float* scores = (float*)(zone2 + NSS * 2);
  // phase-1 occupants (dead before their aliasing writer runs):
  u16*   q_pair   = (u16*)zone2;                        // == attn region
  char*  z3       = zone2 + NSS * 2;                    // == scores region
  u16*   v_b      = (u16*)z3;                           // 16.8 MB
  u16*   Wv_b     = (u16*)(z3 + NSF * 2);               // 2.1 MB
  u16*   WqT_pair = (u16*)(z3 + NSF * 2 + NFF * 2);     // 4.2 MB
  u16*   WkT_pair = WqT_pair + 2 * NFF;                 // 4.2 MB
  float* b_vec    = (float*)(WkT_pair + 2 * NFF);       // 4 KB
  float* Mt_part  = (float*)((char*)b_vec + 4096);      // 4 x 4.2 MB
  u16*   Mt_pair  = (u16*)((char*)Mt_part + 4 * NFF * 4);

  dim3 blk(256);

  // 1) prep: v/Wv split, Wq/Wk transpose+dual-split
  prep_kernel<<<dim3(5120), blk, 0, stream>>>(
      v, Wv, Wq, Wk, v_b, Wv_b, WqT_pair, WkT_pair);

  // 2) b = Wk^T bq (parallel, from WkT_pair hi+lo)
  bvec_kernel<<<dim3(256), blk, 0, stream>>>(WkT_pair, bq, b_vec);

  // 4) split q,k (dual) + kb[row] = k_row . b
  split_qk_kernel<<<dim3(8192), blk, 0, stream>>>(q, k, b_vec, q_pair, k_pair, kb);

  // 5) Mt partials: Mt[e,f] = sum_g Wk[g,e]Wq[g,f], K split 4x256
  gemm_nt<true, 2><<<dim3(F / BN, F / BM, 4), blk, 0, stream>>>(
      WkT_pair, WqT_pair, nullptr, nullptr, Mt_part,
      F, F, 256, F, 512, 512, NFF, 0, S);

  // 6) Mt_pair = dual-split(sum of partials)
  reduce_split_kernel<<<dim3(512), blk, 0, stream>>>(Mt_part, Mt_pair, NFF);

  // 3+7 fused) vpT = Wv v^T + bv  AND  tmp = q @ Mt^T (co-resident 4 blocks/CU)
  gemm_step37<<<dim3(1024), blk, 0, stream>>>(
      Wv_b, v_b, bv, vpT, q_pair, Mt_pair, tmp_pair);

  // 8) scores[z] = tmp[z] @ k[z]^T + kb[z][:]  (fp32) — verified 128^2 4-block/CU
  gemm_nt<true, 2><<<dim3(S / BN, S / BM, B), blk, 0, stream>>>(
      tmp_pair, k_pair, kb, nullptr, scores,
      S, S, F, F, (long)S * 2 * F, (long)S * 2 * F, (long)S * S, 0, S);

  // 9) attn = softmax(scores) (bf16)
  softmax_kernel<<<dim3(B * S), blk, 0, stream>>>(scores, attn, S);

  // 10) out[z] = attn[z] @ vp[z] + q[z] — 64x128 tile, 1024 blocks = 4/CU
  gemm_nt64<<<dim3(F / 128, S / 64, B), blk, 0, stream>>>(
      attn, vpT, q, out,
      F, S, S, (long)S * S, (long)F * S, (long)S * F, (long)S * F);
}

// Round 8
// 413.507 us; speedup vs baseline: 1.1595x; 1.0057x over previous
//
#include <hip/hip_runtime.h>

typedef unsigned short u16;
typedef __bf16 bf16x8 __attribute__((ext_vector_type(8)));
typedef float f32x4 __attribute__((ext_vector_type(4)));
typedef u16 u16x8 __attribute__((ext_vector_type(8)));

union B8 { u16x8 u; bf16x8 b; };

__device__ __forceinline__ u16 f2b(float f){
  unsigned u = __float_as_uint(f);
  return (u16)((u + 0x7FFFu + ((u >> 16) & 1u)) >> 16);
}
__device__ __forceinline__ float b2f(u16 h){ return __uint_as_float(((unsigned)h) << 16); }

__device__ __forceinline__ void gload16(const u16* g, u16* l){
  __builtin_amdgcn_global_load_lds((const __attribute__((address_space(1))) void*)g,
                                   (__attribute__((address_space(3))) void*)l, 16, 0, 0);
}

// ---------------- prep kernel ----------------
// blocks: [0,4096) v->v_b single | [4096,4608) Wv->Wv_b single |
//         [4608,5120) transpose+dual-split Wq->WqT_pair, Wk->WkT_pair
__global__ __launch_bounds__(256) void prep_kernel(
    const float* __restrict__ v, const float* __restrict__ Wv,
    const float* __restrict__ Wq, const float* __restrict__ Wk,
    u16* __restrict__ v_b, u16* __restrict__ Wv_b,
    u16* __restrict__ WqT_pair, u16* __restrict__ WkT_pair)
{
  __shared__ float lds[64][65];
  const int blk = blockIdx.x, t = threadIdx.x;
  if (blk < 4608){
    const float* src; u16* dst; long base;
    if (blk < 4096){ src = v;  dst = v_b;  base = blk; }
    else           { src = Wv; dst = Wv_b; base = blk - 4096; }
    long i = base * 256 + t;
    float4 x0 = ((const float4*)src)[2 * i];
    float4 x1 = ((const float4*)src)[2 * i + 1];
    float xs[8] = {x0.x, x0.y, x0.z, x0.w, x1.x, x1.y, x1.z, x1.w};
    u16x8 h;
    #pragma unroll
    for (int j = 0; j < 8; j++) h[j] = f2b(xs[j]);
    ((u16x8*)dst)[i] = h;
  } else {
    int tt = blk - 4608;
    const float* W = (tt >> 8) ? Wk : Wq;
    u16* outp      = (tt >> 8) ? WkT_pair : WqT_pair;
    int t16 = tt & 255, g0 = (t16 >> 4) * 64, f0 = (t16 & 15) * 64;
    int c4 = (t & 15) * 4, r0 = t >> 4;
    #pragma unroll
    for (int it = 0; it < 4; it++){
      int r = r0 + it * 16;
      float4 x = *(const float4*)&W[(long)(g0 + r) * 1024 + f0 + c4];
      lds[r][c4] = x.x; lds[r][c4+1] = x.y; lds[r][c4+2] = x.z; lds[r][c4+3] = x.w;
    }
    __syncthreads();
    #pragma unroll
    for (int it = 0; it < 2; it++){
      int task = t + it * 256;           // 512 tasks = 64 f-rows x 8 g-groups
      int fl = task >> 3, gi = task & 7;
      u16x8 h, l;
      #pragma unroll
      for (int jj = 0; jj < 8; jj++){
        float xv = lds[gi * 8 + jj][fl];
        h[jj] = f2b(xv); l[jj] = f2b(xv - b2f(h[jj]));
      }
      u16* o = outp + (long)(f0 + fl) * 2048 + ((g0 >> 3) + gi) * 16;
      *(u16x8*)o = h;
      *(u16x8*)(o + 8) = l;
    }
  }
}

// ---------------- XCD-aware block remap (verified R3: FETCH 368->71 MB) ----------------
__device__ __forceinline__ void xcd_remap(int& tx, int& ty, int& tz){
  const int GX = gridDim.x, GY = gridDim.y;
  int b  = blockIdx.x + GX * (blockIdx.y + GY * blockIdx.z);
  int NB = GX * GY * gridDim.z;
  int rank = (b & 7) * (NB >> 3) + (b >> 3);
  int pz = GX * GY;
  tz = rank / pz;
  int r = rank - tz * pz;
  ty = r / GX;
  tx = r - ty * GX;
}

// ---------------- NT GEMM body: C[m][n] = sum_k A[m][k] * B[n][k] ----------------
// EPI: 0 = +bias[n] (nullable), write paired hi|lo (batched by sOb)
//      2 = (+ per-(z,n) col bias if non-null) write fp32 C (batched by sOb)
//      3 = + residual, write fp32 C (batched)
//      4 = +bias[m], write bf16 batch-transposed: out[(n/seq)][m][n%seq] (coalesced in n)
constexpr int BM = 128, BN = 128, BK = 32;

__device__ __forceinline__ int lds1_idx(int row, int g){ return row * 32 + g * 8; }
__device__ __forceinline__ int lds2_idx(int row, int g){
  return row * 64 + (((g ^ (row & 7)) & 7) << 3);
}

// NOTE: 4 blocks/CU. (256,8) capped unified VGPR+AGPR at 64/wave -> spill. Do not
// raise. R2/R3: 256^2 1-block/CU pipelined variants measured 101/95 us vs 90 here.
// R5: A-direct-from-global measured 160 us (uncoalesced frag loads). R6: fusing the
// memory-bound split into a 32KB-LDS kernel halved its occupancy and regressed.
// Keep 128^2 staged, 4 blocks/CU, launch-level co-scheduling only.
template<bool DUAL, int EPI>
__device__ __forceinline__ void gemm_nt_body(
    int tx, int ty, int tz, u16* __restrict__ lds0, u16* __restrict__ lds1,
    const u16* __restrict__ A, const u16* __restrict__ Bm,
    const float* __restrict__ bias, const float* __restrict__ residual,
    void* __restrict__ out0,
    int M, int N, int K, int Krow,
    long sAb, long sBb, long sOb, long sRb, int seq)
{
  const int t = threadIdx.x;
  const int tileM = ty * BM;
  const int tileN = tx * BN;
  const long rs = DUAL ? 2L * Krow : (long)Krow;

  const u16* gA = A  + tz * sAb + (long)tileM * rs;
  const u16* gB = Bm + tz * sBb + (long)tileN * rs;

  const int wave = t >> 6, lane = t & 63;
  const int wm = (wave >> 1) * 64, wn = (wave & 1) * 64;
  const int lr = lane & 15;
  const int lg = lane >> 4;

  const u16 *pa, *pb;
  long jstride;
  int  ldsbase, ldsstep, nissue, kadv;
  if (DUAL){
    const int lr8 = lane >> 3, sl = lane & 7;
    const int g = sl ^ lr8;
    pa = gA + (long)(wave * 32 + lr8) * rs + g * 8;
    pb = gB + (long)(wave * 32 + lr8) * rs + g * 8;
    jstride = 8 * rs;
    ldsbase = (wave * 32) * 64; ldsstep = 8 * 64;
    nissue = 4; kadv = 64;
  } else {
    pa = gA + (long)(wave * 32 + (lane >> 2)) * rs + (lane & 3) * 8;
    pb = gB + (long)(wave * 32 + (lane >> 2)) * rs + (lane & 3) * 8;
    jstride = 16 * rs;
    ldsbase = (wave * 32) * 32; ldsstep = 16 * 32;
    nissue = 2; kadv = 32;
  }

  f32x4 acc[4][4] = {};

  for (int k0 = 0; k0 < K; k0 += BK){
    __syncthreads();
    #pragma unroll 4
    for (int j = 0; j < nissue; j++){
      gload16(pa + j * jstride, &lds0[ldsbase + j * ldsstep]);
      gload16(pb + j * jstride, &lds1[ldsbase + j * ldsstep]);
    }
    pa += kadv; pb += kadv;
    __syncthreads();

    if (DUAL){
      B8 ah[4], al[4], bh[4], bl[4];
      #pragma unroll
      for (int mt = 0; mt < 4; mt++){
        int row = wm + mt * 16 + lr;
        ah[mt].u = *(const u16x8*)&lds0[lds2_idx(row, lg * 2)];
        al[mt].u = *(const u16x8*)&lds0[lds2_idx(row, lg * 2 + 1)];
      }
      #pragma unroll
      for (int nt = 0; nt < 4; nt++){
        int row = wn + nt * 16 + lr;
        bh[nt].u = *(const u16x8*)&lds1[lds2_idx(row, lg * 2)];
        bl[nt].u = *(const u16x8*)&lds1[lds2_idx(row, lg * 2 + 1)];
      }
      #pragma unroll
      for (int mt = 0; mt < 4; mt++){
        #pragma unroll
        for (int nt = 0; nt < 4; nt++){
          acc[mt][nt] = __builtin_amdgcn_mfma_f32_16x16x32_bf16(ah[mt].b, bh[nt].b, acc[mt][nt], 0, 0, 0);
          acc[mt][nt] = __builtin_amdgcn_mfma_f32_16x16x32_bf16(ah[mt].b, bl[nt].b, acc[mt][nt], 0, 0, 0);
          acc[mt][nt] = __builtin_amdgcn_mfma_f32_16x16x32_bf16(al[mt].b, bh[nt].b, acc[mt][nt], 0, 0, 0);
        }
      }
    } else {
      B8 af[4], bf[4];
      #pragma unroll
      for (int mt = 0; mt < 4; mt++)
        af[mt].u = *(const u16x8*)&lds0[lds1_idx(wm + mt * 16 + lr, lg)];
      #pragma unroll
      for (int nt = 0; nt < 4; nt++)
        bf[nt].u = *(const u16x8*)&lds1[lds1_idx(wn + nt * 16 + lr, lg)];
      #pragma unroll
      for (int mt = 0; mt < 4; mt++)
        #pragma unroll
        for (int nt = 0; nt < 4; nt++)
          acc[mt][nt] = __builtin_amdgcn_mfma_f32_16x16x32_bf16(af[mt].b, bf[nt].b, acc[mt][nt], 0, 0, 0);
    }
  }

  // epilogue: C/D layout col=lane&15, row=(lane>>4)*4+reg  [m89-verified]
  const int rq = lg * 4;
  #pragma unroll
  for (int nt = 0; nt < 4; nt++){
    const int n = tileN + wn + nt * 16 + lr;
    float bv = 0.f;
    if (EPI == 0 && bias) bv = bias[n];
    if (EPI == 2 && bias) bv = bias[(long)tz * N + n];
    #pragma unroll
    for (int mt = 0; mt < 4; mt++){
      #pragma unroll
      for (int r = 0; r < 4; r++){
        const int m = tileM + wm + mt * 16 + rq + r;
        float val = acc[mt][nt][r] + bv;
        if (EPI == 0){
          u16 h = f2b(val);
          u16* o = (u16*)out0 + (long)tz * sOb + (long)m * 2 * N + ((n >> 3) << 4) + (n & 7);
          o[0] = h;
          o[8] = f2b(val - b2f(h));
        } else if (EPI == 2){
          ((float*)out0)[(long)tz * sOb + (long)m * N + n] = val;
        } else if (EPI == 3){
          float res = residual[(long)tz * sRb + (long)m * N + n];
          ((float*)out0)[(long)tz * sOb + (long)m * N + n] = val + res;
        } else {  // EPI == 4: transposed-coalesced bf16, bias by m
          if (bias) val += bias[m];
          long idx = (long)(n / seq) * ((long)M * seq) + (long)m * seq + (n % seq);
          ((u16*)out0)[idx] = f2b(val);
        }
      }
    }
  }
}

template<bool DUAL, int EPI>
__global__ __launch_bounds__(256, 4)
void gemm_nt(const u16* __restrict__ A, const u16* __restrict__ Bm,
             const float* __restrict__ bias, const float* __restrict__ residual,
             void* __restrict__ out0,
             int M, int N, int K, int Krow,
             long sAb, long sBb, long sOb, long sRb, int seq)
{
  constexpr int RW = DUAL ? 64 : 32;
  __shared__ u16 sh[2 * BM * RW];
  int tx, ty, tz; xcd_remap(tx, ty, tz);
  gemm_nt_body<DUAL, EPI>(tx, ty, tz, sh, sh + BM * RW,
                          A, Bm, bias, residual, out0,
                          M, N, K, Krow, sAb, sBb, sOb, sRb, seq);
}

// ---------------- fused: bvec (256 blocks) + step 5 (256 blocks) ----------------
// Both depend only on prep's WkT/WqT outputs and were serial narrow launches
// (bvec ~3us alone; step 5 at 1 block/CU alone). Co-resident they overlap.
// Step-5 block mapping replicates grid(8,8,4)+xcd_remap exactly (bitwise-same).
__global__ __launch_bounds__(256, 4)
void fused_bvec_s5(const u16* __restrict__ WkT_pair, const u16* __restrict__ WqT_pair,
                   const float* __restrict__ bq,
                   float* __restrict__ b_vec, float* __restrict__ Mt_part)
{
  __shared__ u16 sh[2 * BM * 64];   // 32 KB, gemm path only
  const int blk = blockIdx.x, t = threadIdx.x;
  if (blk < 256){
    // bvec: b[e] = sum_g Wk[g][e]*bq[g] from WkT_pair hi+lo
    const int wave = t >> 6, lane = t & 63;
    const int e = blk * 4 + wave;
    const u16* row = WkT_pair + (long)e * 2048;
    float acc = 0.f;
    #pragma unroll
    for (int ii = 0; ii < 2; ii++){
      int gi = lane * 2 + ii;
      const u16* p = row + gi * 16;
      #pragma unroll
      for (int j = 0; j < 8; j++)
        acc += (b2f(p[j]) + b2f(p[j + 8])) * bq[gi * 8 + j];
    }
    #pragma unroll
    for (int off = 32; off > 0; off >>= 1) acc += __shfl_xor(acc, off, 64);
    if (lane == 0) b_vec[e] = acc;
    return;
  }
  // step 5: Mt[e,f] partials, K split 4x256 — replica of grid (8,8,4) + xcd_remap
  const int b = blk - 256;
  const int rank = (b & 7) * 32 + (b >> 3);
  const int tz = rank >> 6, rem = rank & 63;
  gemm_nt_body<true, 2>(rem & 7, rem >> 3, tz, sh, sh + BM * 64,
                        WkT_pair, WqT_pair, nullptr, nullptr, Mt_part,
                        1024, 1024, 256, 1024, 512, 512, 1024L * 1024, 0, 2048);
}

// ---------------- fused: split q,k + kb (8192 blocks) + reduce_split (512) --------
// split needs b_vec (prev launch); reduce needs Mt_part (prev launch). Independent
// of each other -> one launch, reduce hides inside split's memory phase.
// Tiny LDS only (R6 lesson: never give memory-bound blocks a 32KB allocation).
__global__ __launch_bounds__(256)
void fused_split_reduce(const float* __restrict__ q, const float* __restrict__ kk,
                        const float* __restrict__ b,
                        u16* __restrict__ q_pair, u16* __restrict__ k_pair,
                        float* __restrict__ kb,
                        const float* __restrict__ part, u16* __restrict__ out_pair,
                        long nper)
{
  __shared__ float red[4];
  const int blk = blockIdx.x, t = threadIdx.x;
  if (blk < 8192){
    const bool isK = blk >= 4096;
    const float* src = isK ? kk : q;
    u16* dst = isK ? k_pair : q_pair;
    long base = isK ? blk - 4096 : blk;
    long i = base * 256 + t;
    float4 x0 = ((const float4*)src)[2 * i];
    float4 x1 = ((const float4*)src)[2 * i + 1];
    float xs[8] = {x0.x, x0.y, x0.z, x0.w, x1.x, x1.y, x1.z, x1.w};
    u16x8 h, l;
    #pragma unroll
    for (int j = 0; j < 8; j++){ h[j] = f2b(xs[j]); l[j] = f2b(xs[j] - b2f(h[j])); }
    ((u16x8*)dst)[2 * i]     = h;
    ((u16x8*)dst)[2 * i + 1] = l;
    if (isK){
      const int f = (t & 127) * 8;
      float d = 0.f;
      #pragma unroll
      for (int j = 0; j < 8; j++) d += xs[j] * b[f + j];
      #pragma unroll
      for (int off = 32; off > 0; off >>= 1) d += __shfl_xor(d, off, 64);
      if ((t & 63) == 0) red[t >> 6] = d;
      __syncthreads();
      if (t == 0)   kb[base * 2]     = red[0] + red[1];
      if (t == 128) kb[base * 2 + 1] = red[2] + red[3];
    }
    return;
  }
  // reduce: 4 fp32 partials -> dual pair
  long i = (long)(blk - 8192) * 256 + t;
  float s[8];
  #pragma unroll
  for (int j = 0; j < 8; j++) s[j] = 0.f;
  #pragma unroll
  for (int z = 0; z < 4; z++){
    float4 a0 = ((const float4*)(part + z * nper))[2 * i];
    float4 a1 = ((const float4*)(part + z * nper))[2 * i + 1];
    s[0]+=a0.x; s[1]+=a0.y; s[2]+=a0.z; s[3]+=a0.w;
    s[4]+=a1.x; s[5]+=a1.y; s[6]+=a1.z; s[7]+=a1.w;
  }
  u16x8 h, l;
  #pragma unroll
  for (int j = 0; j < 8; j++){ h[j] = f2b(s[j]); l[j] = f2b(s[j] - b2f(h[j])); }
  long e = (i * 8) >> 10;
  long g = i & 127;
  u16* o = out_pair + e * 2048 + g * 16;
  *(u16x8*)o = h;
  *(u16x8*)(o + 8) = l;
}

// ---------------- fused steps 3+7: two independent 512-block GEMMs ----------------
// Each alone fills only 2 blocks/CU; fused 1024-block launch co-resides both at 4/CU.
__global__ __launch_bounds__(256, 4)
void gemm_step37(const u16* __restrict__ Wv_b, const u16* __restrict__ v_b,
                 const float* __restrict__ bv, u16* __restrict__ vpT,
                 const u16* __restrict__ q_pair, const u16* __restrict__ Mt_pair,
                 u16* __restrict__ tmp_pair)
{
  __shared__ u16 sh[2 * BM * 64];   // 32 KB: dual needs full, single uses half-stride
  const int b = blockIdx.x, xcd = b & 7, i = b >> 3;
  if (i < 64){
    // step 3: vpT = Wv_b @ v_b^T + bv, EPI4, grid was (64, 8): tx = rank&63, ty = rank>>6
    const int rank = xcd * 64 + i;
    gemm_nt_body<false, 4>(rank & 63, rank >> 6, 0, sh, sh + BM * 32,
                           Wv_b, v_b, bv, nullptr, vpT,
                           1024, 8192, 1024, 1024, 0, 0, 0, 0, 2048);
  } else {
    // step 7: tmp_pair = q_pair @ Mt_pair^T, EPI0, grid was (8, 64): tx = rank&7, ty = rank>>3
    const int rank = xcd * 64 + (i - 64);
    gemm_nt_body<true, 0>(rank & 7, rank >> 3, 0, sh, sh + BM * 64,
                          q_pair, Mt_pair, nullptr, nullptr, tmp_pair,
                          8192, 1024, 1024, 1024, 0, 0, 0, 0, 2048);
  }
}

// ---------------- step 10: 64x128 single GEMM, 4 blocks/CU + chunk swizzle ---------
// out[z][m][n] = sum_k attn[z][m][k] * vpT[z][n][k] + q[z][m][n]
// BM=64 doubles the grid to 1024 blocks (4/CU vs 2/CU for the 128^2 shape). [R7 WIN]
__global__ __launch_bounds__(256, 4)
void gemm_nt64(const u16* __restrict__ A, const u16* __restrict__ Bm,
               const float* __restrict__ residual, float* __restrict__ out,
               int N, int K, int Krow, long sAb, long sBb, long sOb, long sRb)
{
  __shared__ u16 ldsA[64 * 32];    // 4 KB
  __shared__ u16 ldsB[128 * 32];   // 8 KB

  int tx, ty, tz; xcd_remap(tx, ty, tz);
  const int t = threadIdx.x;
  const int tileM = ty * 64, tileN = tx * 128;
  const long rs = (long)Krow;

  const u16* gA = A  + tz * sAb + (long)tileM * rs;
  const u16* gB = Bm + tz * sBb + (long)tileN * rs;

  const int wave = t >> 6, lane = t & 63;
  const int wm = (wave >> 1) * 32, wn = (wave & 1) * 64;
  const int lr = lane & 15, lg = lane >> 4;

  const int srow = lane >> 2;
  const int schunk = (lane & 3) ^ (srow & 3);
  const u16* pa = gA + (long)(wave * 16 + srow) * rs + schunk * 8;
  const u16* pb = gB + (long)(wave * 32 + srow) * rs + schunk * 8;
  const int ldsbaseA = (wave * 16) * 32;
  const int ldsbaseB = (wave * 32) * 32;

  f32x4 acc[2][4] = {};

  for (int k0 = 0; k0 < K; k0 += 32){
    __syncthreads();
    gload16(pa,           &ldsA[ldsbaseA]);
    gload16(pb,           &ldsB[ldsbaseB]);
    gload16(pb + 16 * rs, &ldsB[ldsbaseB + 16 * 32]);
    pa += 32; pb += 32;
    __syncthreads();

    B8 af[2], bf[4];
    #pragma unroll
    for (int mt = 0; mt < 2; mt++){
      int row = wm + mt * 16 + lr;
      af[mt].u = *(const u16x8*)&ldsA[row * 32 + ((lg ^ (row & 3)) & 3) * 8];
    }
    #pragma unroll
    for (int nt = 0; nt < 4; nt++){
      int row = wn + nt * 16 + lr;
      bf[nt].u = *(const u16x8*)&ldsB[row * 32 + ((lg ^ (row & 3)) & 3) * 8];
    }
    #pragma unroll
    for (int mt = 0; mt < 2; mt++)
      #pragma unroll
      for (int nt = 0; nt < 4; nt++)
        acc[mt][nt] = __builtin_amdgcn_mfma_f32_16x16x32_bf16(af[mt].b, bf[nt].b, acc[mt][nt], 0, 0, 0);
  }

  const int rq = lg * 4;
  #pragma unroll
  for (int nt = 0; nt < 4; nt++){
    const int n = tileN + wn + nt * 16 + lr;
    #pragma unroll
    for (int mt = 0; mt < 2; mt++){
      #pragma unroll
      for (int r = 0; r < 4; r++){
        const int m = tileM + wm + mt * 16 + rq + r;
        float res = residual[(long)tz * sRb + (long)m * N + n];
        out[(long)tz * sOb + (long)m * N + n] = acc[mt][nt][r] + res;
      }
    }
  }
}

// ---------------- row softmax: fp32 scores -> bf16 probs (n == 2048) ----------------
__global__ __launch_bounds__(256)
void softmax_kernel(const float* __restrict__ S, u16* __restrict__ P, int n){
  const long row = blockIdx.x;
  const float* r = S + row * (long)n;
  const int t = threadIdx.x;
  float v[8];
  float mx = -3.0e38f;
  #pragma unroll
  for (int i = 0; i < 8; i++){ v[i] = r[t + (i << 8)]; mx = fmaxf(mx, v[i]); }
  #pragma unroll
  for (int off = 32; off > 0; off >>= 1) mx = fmaxf(mx, __shfl_xor(mx, off, 64));
  __shared__ float red[8];
  const int wave = t >> 6;
  if ((t & 63) == 0) red[wave] = mx;
  __syncthreads();
  mx = fmaxf(fmaxf(red[0], red[1]), fmaxf(red[2], red[3]));
  float s = 0.f;
  #pragma unroll
  for (int i = 0; i < 8; i++){ v[i] = __expf(v[i] - mx); s += v[i]; }
  #pragma unroll
  for (int off = 32; off > 0; off >>= 1) s += __shfl_xor(s, off, 64);
  if ((t & 63) == 0) red[4 + wave] = s;
  __syncthreads();
  s = red[4] + red[5] + red[6] + red[7];
  const float inv = 1.f / s;
  u16* pr = P + row * (long)n;
  #pragma unroll
  for (int i = 0; i < 8; i++) pr[t + (i << 8)] = f2b(v[i] * inv);
}

extern "C" void kernel_launch(void* const* d_in, const int* in_sizes, int n_in,
                              void* d_out, int out_size, void* d_ws, size_t ws_size,
                              hipStream_t stream){
  (void)in_sizes; (void)n_in; (void)out_size; (void)ws_size;
  const float* q  = (const float*)d_in[0];
  const float* k  = (const float*)d_in[1];
  const float* v  = (const float*)d_in[2];
  const float* Wq = (const float*)d_in[3];
  const float* bq = (const float*)d_in[4];
  const float* Wk = (const float*)d_in[5];
  // bk enters only a row-constant term: softmax-invariant, dropped
  const float* Wv = (const float*)d_in[7];
  const float* bv = (const float*)d_in[8];
  float* out = (float*)d_out;

  const int B = 4, S = 2048, F = 1024;
  const long NSF = (long)B * S * F;   // 8 Mi
  const long NFF = (long)F * F;       // 1 Mi
  const long NSS = (long)B * S * S;   // 16 Mi

  char* w = (char*)d_ws;
  auto alloc = [&](long bytes) -> char* {
    char* p = w; w += (bytes + 255) & ~(long)255; return p;
  };
  // persistent
  u16*   tmp_pair = (u16*)alloc(2 * NSF * 2);   // (q M^T) dual pair, 33.5 MB
  u16*   k_pair   = (u16*)alloc(2 * NSF * 2);   // raw k dual pair,   33.5 MB
  u16*   vpT      = (u16*)alloc(NSF * 2);       // 16.8 MB
  float* kb       = (float*)alloc((long)B * S * 4);
  // zone2 (100.7 MB): scores+attn alias the phase-1 temporaries
  char* zone2 = alloc(NSS * 2 + NSS * 4);
  u16*   attn   = (u16*)zone2;
  float* scores = (float*)(zone2 + NSS * 2);
  // phase-1 occupants (dead before their aliasing writer runs):
  u16*   q_pair   = (u16*)zone2;                        // == attn region
  char*  z3       = zone2 + NSS * 2;                    // == scores region
  u16*   v_b      = (u16*)z3;                           // 16.8 MB
  u16*   Wv_b     = (u16*)(z3 + NSF * 2);               // 2.1 MB
  u16*   WqT_pair = (u16*)(z3 + NSF * 2 + NFF * 2);     // 4.2 MB
  u16*   WkT_pair = WqT_pair + 2 * NFF;                 // 4.2 MB
  float* b_vec    = (float*)(WkT_pair + 2 * NFF);       // 4 KB
  float* Mt_part  = (float*)((char*)b_vec + 4096);      // 4 x 4.2 MB
  u16*   Mt_pair  = (u16*)((char*)Mt_part + 4 * NFF * 4);

  dim3 blk(256);

  // 1) prep: v/Wv split, Wq/Wk transpose+dual-split
  prep_kernel<<<dim3(5120), blk, 0, stream>>>(
      v, Wv, Wq, Wk, v_b, Wv_b, WqT_pair, WkT_pair);

  // 2+5 fused) b_vec = Wk^T bq  AND  Mt partials (co-resident)
  fused_bvec_s5<<<dim3(512), blk, 0, stream>>>(
      WkT_pair, WqT_pair, bq, b_vec, Mt_part);

  // 4+6 fused) split q,k (dual) + kb  AND  Mt_pair = dual-split(sum of partials)
  fused_split_reduce<<<dim3(8704), blk, 0, stream>>>(
      q, k, b_vec, q_pair, k_pair, kb, Mt_part, Mt_pair, NFF);

  // 3+7 fused) vpT = Wv v^T + bv  AND  tmp = q @ Mt^T (co-resident 4 blocks/CU)
  gemm_step37<<<dim3(1024), blk, 0, stream>>>(
      Wv_b, v_b, bv, vpT, q_pair, Mt_pair, tmp_pair);

  // 8) scores[z] = tmp[z] @ k[z]^T + kb[z][:]  (fp32) — verified 128^2 4-block/CU
  gemm_nt<true, 2><<<dim3(S / BN, S / BM, B), blk, 0, stream>>>(
      tmp_pair, k_pair, kb, nullptr, scores,
      S, S, F, F, (long)S * 2 * F, (long)S * 2 * F, (long)S * S, 0, S);

  // 9) attn = softmax(scores) (bf16)
  softmax_kernel<<<dim3(B * S), blk, 0, stream>>>(scores, attn, S);

  // 10) out[z] = attn[z] @ vp[z] + q[z] — 64x128 tile, 1024 blocks = 4/CU
  gemm_nt64<<<dim3(F / 128, S / 64, B), blk, 0, stream>>>(
      attn, vpT, q, out,
      F, S, S, (long)S * S, (long)F * S, (long)S * F, (long)S * F);
}

// Round 9
// 387.698 us; speedup vs baseline: 1.2366x; 1.0666x over previous
//
#include <hip/hip_runtime.h>

typedef unsigned short u16;
typedef __bf16 bf16x8 __attribute__((ext_vector_type(8)));
typedef float f32x4 __attribute__((ext_vector_type(4)));
typedef u16 u16x8 __attribute__((ext_vector_type(8)));

union B8 { u16x8 u; bf16x8 b; };

__device__ __forceinline__ u16 f2b(float f){
  unsigned u = __float_as_uint(f);
  return (u16)((u + 0x7FFFu + ((u >> 16) & 1u)) >> 16);
}
__device__ __forceinline__ float b2f(u16 h){ return __uint_as_float(((unsigned)h) << 16); }

__device__ __forceinline__ void gload16(const u16* g, u16* l){
  __builtin_amdgcn_global_load_lds((const __attribute__((address_space(1))) void*)g,
                                   (__attribute__((address_space(3))) void*)l, 16, 0, 0);
}

// ---------------- prep kernel ----------------
// blocks: [0,4096) v->v_b single | [4096,4608) Wv->Wv_b single |
//         [4608,5120) transpose+dual-split Wq->WqT_pair, Wk->WkT_pair
__global__ __launch_bounds__(256) void prep_kernel(
    const float* __restrict__ v, const float* __restrict__ Wv,
    const float* __restrict__ Wq, const float* __restrict__ Wk,
    u16* __restrict__ v_b, u16* __restrict__ Wv_b,
    u16* __restrict__ WqT_pair, u16* __restrict__ WkT_pair)
{
  __shared__ float lds[64][65];
  const int blk = blockIdx.x, t = threadIdx.x;
  if (blk < 4608){
    const float* src; u16* dst; long base;
    if (blk < 4096){ src = v;  dst = v_b;  base = blk; }
    else           { src = Wv; dst = Wv_b; base = blk - 4096; }
    long i = base * 256 + t;
    float4 x0 = ((const float4*)src)[2 * i];
    float4 x1 = ((const float4*)src)[2 * i + 1];
    float xs[8] = {x0.x, x0.y, x0.z, x0.w, x1.x, x1.y, x1.z, x1.w};
    u16x8 h;
    #pragma unroll
    for (int j = 0; j < 8; j++) h[j] = f2b(xs[j]);
    ((u16x8*)dst)[i] = h;
  } else {
    int tt = blk - 4608;
    const float* W = (tt >> 8) ? Wk : Wq;
    u16* outp      = (tt >> 8) ? WkT_pair : WqT_pair;
    int t16 = tt & 255, g0 = (t16 >> 4) * 64, f0 = (t16 & 15) * 64;
    int c4 = (t & 15) * 4, r0 = t >> 4;
    #pragma unroll
    for (int it = 0; it < 4; it++){
      int r = r0 + it * 16;
      float4 x = *(const float4*)&W[(long)(g0 + r) * 1024 + f0 + c4];
      lds[r][c4] = x.x; lds[r][c4+1] = x.y; lds[r][c4+2] = x.z; lds[r][c4+3] = x.w;
    }
    __syncthreads();
    #pragma unroll
    for (int it = 0; it < 2; it++){
      int task = t + it * 256;           // 512 tasks = 64 f-rows x 8 g-groups
      int fl = task >> 3, gi = task & 7;
      u16x8 h, l;
      #pragma unroll
      for (int jj = 0; jj < 8; jj++){
        float xv = lds[gi * 8 + jj][fl];
        h[jj] = f2b(xv); l[jj] = f2b(xv - b2f(h[jj]));
      }
      u16* o = outp + (long)(f0 + fl) * 2048 + ((g0 >> 3) + gi) * 16;
      *(u16x8*)o = h;
      *(u16x8*)(o + 8) = l;
    }
  }
}

// ---------------- XCD-aware block remap (verified R3: FETCH 368->71 MB) ----------------
__device__ __forceinline__ void xcd_remap(int& tx, int& ty, int& tz){
  const int GX = gridDim.x, GY = gridDim.y;
  int b  = blockIdx.x + GX * (blockIdx.y + GY * blockIdx.z);
  int NB = GX * GY * gridDim.z;
  int rank = (b & 7) * (NB >> 3) + (b >> 3);
  int pz = GX * GY;
  tz = rank / pz;
  int r = rank - tz * pz;
  ty = r / GX;
  tx = r - ty * GX;
}

// ---------------- NT GEMM body: C[m][n] = sum_k A[m][k] * B[n][k] ----------------
// EPI: 0 = +bias[n] (nullable), write paired hi|lo (batched by sOb)
//      2 = (+ per-(z,n) col bias if non-null) write fp32 C (batched by sOb)
//      3 = + residual, write fp32 C (batched)
//      4 = +bias[m], write bf16 batch-transposed: out[(n/seq)][m][n%seq] (coalesced in n)
constexpr int BM = 128, BN = 128, BK = 32;

__device__ __forceinline__ int lds1_idx(int row, int g){ return row * 32 + g * 8; }
__device__ __forceinline__ int lds2_idx(int row, int g){
  return row * 64 + (((g ^ (row & 7)) & 7) << 3);
}

// NOTE: 4 blocks/CU. (256,8) capped unified VGPR+AGPR at 64/wave -> spill. Do not
// raise. R2/R3: 256^2 1-block/CU pipelined variants measured 101/95 us vs 90 here.
// R5: A-direct-from-global measured 160 us (uncoalesced frag loads). R6: fusing the
// memory-bound split into a 32KB-LDS kernel halved its occupancy and regressed.
// Catalog regime-gate: T2/T3/T5 measured-NULL on 2-barrier structures -> no swizzle
// or pipelining surgery here. Keep 128^2 staged, 4 blocks/CU.
template<bool DUAL, int EPI>
__device__ __forceinline__ void gemm_nt_body(
    int tx, int ty, int tz, u16* __restrict__ lds0, u16* __restrict__ lds1,
    const u16* __restrict__ A, const u16* __restrict__ Bm,
    const float* __restrict__ bias, const float* __restrict__ residual,
    void* __restrict__ out0,
    int M, int N, int K, int Krow,
    long sAb, long sBb, long sOb, long sRb, int seq)
{
  const int t = threadIdx.x;
  const int tileM = ty * BM;
  const int tileN = tx * BN;
  const long rs = DUAL ? 2L * Krow : (long)Krow;

  const u16* gA = A  + tz * sAb + (long)tileM * rs;
  const u16* gB = Bm + tz * sBb + (long)tileN * rs;

  const int wave = t >> 6, lane = t & 63;
  const int wm = (wave >> 1) * 64, wn = (wave & 1) * 64;
  const int lr = lane & 15;
  const int lg = lane >> 4;

  const u16 *pa, *pb;
  long jstride;
  int  ldsbase, ldsstep, nissue, kadv;
  if (DUAL){
    const int lr8 = lane >> 3, sl = lane & 7;
    const int g = sl ^ lr8;
    pa = gA + (long)(wave * 32 + lr8) * rs + g * 8;
    pb = gB + (long)(wave * 32 + lr8) * rs + g * 8;
    jstride = 8 * rs;
    ldsbase = (wave * 32) * 64; ldsstep = 8 * 64;
    nissue = 4; kadv = 64;
  } else {
    pa = gA + (long)(wave * 32 + (lane >> 2)) * rs + (lane & 3) * 8;
    pb = gB + (long)(wave * 32 + (lane >> 2)) * rs + (lane & 3) * 8;
    jstride = 16 * rs;
    ldsbase = (wave * 32) * 32; ldsstep = 16 * 32;
    nissue = 2; kadv = 32;
  }

  f32x4 acc[4][4] = {};

  for (int k0 = 0; k0 < K; k0 += BK){
    __syncthreads();
    #pragma unroll 4
    for (int j = 0; j < nissue; j++){
      gload16(pa + j * jstride, &lds0[ldsbase + j * ldsstep]);
      gload16(pb + j * jstride, &lds1[ldsbase + j * ldsstep]);
    }
    pa += kadv; pb += kadv;
    __syncthreads();

    if (DUAL){
      B8 ah[4], al[4], bh[4], bl[4];
      #pragma unroll
      for (int mt = 0; mt < 4; mt++){
        int row = wm + mt * 16 + lr;
        ah[mt].u = *(const u16x8*)&lds0[lds2_idx(row, lg * 2)];
        al[mt].u = *(const u16x8*)&lds0[lds2_idx(row, lg * 2 + 1)];
      }
      #pragma unroll
      for (int nt = 0; nt < 4; nt++){
        int row = wn + nt * 16 + lr;
        bh[nt].u = *(const u16x8*)&lds1[lds2_idx(row, lg * 2)];
        bl[nt].u = *(const u16x8*)&lds1[lds2_idx(row, lg * 2 + 1)];
      }
      #pragma unroll
      for (int mt = 0; mt < 4; mt++){
        #pragma unroll
        for (int nt = 0; nt < 4; nt++){
          acc[mt][nt] = __builtin_amdgcn_mfma_f32_16x16x32_bf16(ah[mt].b, bh[nt].b, acc[mt][nt], 0, 0, 0);
          acc[mt][nt] = __builtin_amdgcn_mfma_f32_16x16x32_bf16(ah[mt].b, bl[nt].b, acc[mt][nt], 0, 0, 0);
          acc[mt][nt] = __builtin_amdgcn_mfma_f32_16x16x32_bf16(al[mt].b, bh[nt].b, acc[mt][nt], 0, 0, 0);
        }
      }
    } else {
      B8 af[4], bf[4];
      #pragma unroll
      for (int mt = 0; mt < 4; mt++)
        af[mt].u = *(const u16x8*)&lds0[lds1_idx(wm + mt * 16 + lr, lg)];
      #pragma unroll
      for (int nt = 0; nt < 4; nt++)
        bf[nt].u = *(const u16x8*)&lds1[lds1_idx(wn + nt * 16 + lr, lg)];
      #pragma unroll
      for (int mt = 0; mt < 4; mt++)
        #pragma unroll
        for (int nt = 0; nt < 4; nt++)
          acc[mt][nt] = __builtin_amdgcn_mfma_f32_16x16x32_bf16(af[mt].b, bf[nt].b, acc[mt][nt], 0, 0, 0);
    }
  }

  // epilogue: C/D layout col=lane&15, row=(lane>>4)*4+reg  [m89-verified]
  const int rq = lg * 4;
  #pragma unroll
  for (int nt = 0; nt < 4; nt++){
    const int n = tileN + wn + nt * 16 + lr;
    float bv = 0.f;
    if (EPI == 0 && bias) bv = bias[n];
    if (EPI == 2 && bias) bv = bias[(long)tz * N + n];
    #pragma unroll
    for (int mt = 0; mt < 4; mt++){
      #pragma unroll
      for (int r = 0; r < 4; r++){
        const int m = tileM + wm + mt * 16 + rq + r;
        float val = acc[mt][nt][r] + bv;
        if (EPI == 0){
          u16 h = f2b(val);
          u16* o = (u16*)out0 + (long)tz * sOb + (long)m * 2 * N + ((n >> 3) << 4) + (n & 7);
          o[0] = h;
          o[8] = f2b(val - b2f(h));
        } else if (EPI == 2){
          ((float*)out0)[(long)tz * sOb + (long)m * N + n] = val;
        } else if (EPI == 3){
          float res = residual[(long)tz * sRb + (long)m * N + n];
          ((float*)out0)[(long)tz * sOb + (long)m * N + n] = val + res;
        } else {  // EPI == 4: transposed-coalesced bf16, bias by m
          if (bias) val += bias[m];
          long idx = (long)(n / seq) * ((long)M * seq) + (long)m * seq + (n % seq);
          ((u16*)out0)[idx] = f2b(val);
        }
      }
    }
  }
}

template<bool DUAL, int EPI>
__global__ __launch_bounds__(256, 4)
void gemm_nt(const u16* __restrict__ A, const u16* __restrict__ Bm,
             const float* __restrict__ bias, const float* __restrict__ residual,
             void* __restrict__ out0,
             int M, int N, int K, int Krow,
             long sAb, long sBb, long sOb, long sRb, int seq)
{
  constexpr int RW = DUAL ? 64 : 32;
  __shared__ u16 sh[2 * BM * RW];
  int tx, ty, tz; xcd_remap(tx, ty, tz);
  gemm_nt_body<DUAL, EPI>(tx, ty, tz, sh, sh + BM * RW,
                          A, Bm, bias, residual, out0,
                          M, N, K, Krow, sAb, sBb, sOb, sRb, seq);
}

// ------- single-path body, BK=64 as TWO BK=32 panels per barrier-pair [R9] -------
// Halves the barrier-pair count for the drain-dominated single-MFMA GEMMs (only
// 16 (BMT=128) or 8 (BMT=64) MFMA/wave amortize each drain, vs dual's 48).
// Panels staged as two independent [rows][32] tiles; inner loop = two copies of
// the BK=32 body in ascending k -> bitwise-identical accumulation order.
// Chunk swizzle (store (lane&3)^(srow&3) via pre-swizzled global src, read
// lg^(row&3)) — placement permutation only.
template<int BMT, int EPI>
__device__ __forceinline__ void gemm_nt1_bk64(
    int tx, int ty, int tz, u16* __restrict__ ldsA, u16* __restrict__ ldsB,
    const u16* __restrict__ A, const u16* __restrict__ Bm,
    const float* __restrict__ bias, const float* __restrict__ residual,
    void* __restrict__ out0,
    int M, int N, int K, int Krow,
    long sAb, long sBb, long sOb, long sRb, int seq)
{
  constexpr int MT = BMT / 32;          // A-frags per wave (2 or 4)
  const int t = threadIdx.x;
  const int tileM = ty * BMT;
  const int tileN = tx * BN;
  const long rs = (long)Krow;

  const u16* gA = A  + tz * sAb + (long)tileM * rs;
  const u16* gB = Bm + tz * sBb + (long)tileN * rs;

  const int wave = t >> 6, lane = t & 63;
  const int wm = (wave >> 1) * (BMT / 2), wn = (wave & 1) * 64;
  const int lr = lane & 15, lg = lane >> 4;

  // staging: srow in [0,16), source chunk pre-swizzled to match read swizzle
  const int srow = lane >> 2;
  const int schunk = (lane & 3) ^ (srow & 3);
  const u16* pa = gA + (long)(wave * (BMT / 4) + srow) * rs + schunk * 8;
  const u16* pb = gB + (long)(wave * 32 + srow) * rs + schunk * 8;
  const int ldsbaseA = (wave * (BMT / 4)) * 32;
  const int ldsbaseB = (wave * 32) * 32;
  constexpr int APANEL = BMT * 32;      // u16 per A panel
  constexpr int BPANEL = 128 * 32;      // u16 per B panel

  f32x4 acc[MT][4] = {};

  for (int k0 = 0; k0 < K; k0 += 64){
    __syncthreads();
    #pragma unroll
    for (int s = 0; s < 2; s++){
      // A panel s: BMT/4 rows per wave per issue, BMT/64 issues
      #pragma unroll
      for (int j = 0; j < BMT / 64; j++)
        gload16(pa + s * 32 + (long)(j * 16) * rs, &ldsA[s * APANEL + ldsbaseA + j * 16 * 32]);
      // B panel s: 32 rows per wave, 2 issues
      #pragma unroll
      for (int j = 0; j < 2; j++)
        gload16(pb + s * 32 + (long)(j * 16) * rs, &ldsB[s * BPANEL + ldsbaseB + j * 16 * 32]);
    }
    pa += 64; pb += 64;
    __syncthreads();

    #pragma unroll
    for (int s = 0; s < 2; s++){
      B8 af[MT], bf[4];
      #pragma unroll
      for (int mt = 0; mt < MT; mt++){
        int row = wm + mt * 16 + lr;
        af[mt].u = *(const u16x8*)&ldsA[s * APANEL + row * 32 + ((lg ^ (row & 3)) & 3) * 8];
      }
      #pragma unroll
      for (int nt = 0; nt < 4; nt++){
        int row = wn + nt * 16 + lr;
        bf[nt].u = *(const u16x8*)&ldsB[s * BPANEL + row * 32 + ((lg ^ (row & 3)) & 3) * 8];
      }
      #pragma unroll
      for (int mt = 0; mt < MT; mt++)
        #pragma unroll
        for (int nt = 0; nt < 4; nt++)
          acc[mt][nt] = __builtin_amdgcn_mfma_f32_16x16x32_bf16(af[mt].b, bf[nt].b, acc[mt][nt], 0, 0, 0);
    }
  }

  const int rq = lg * 4;
  #pragma unroll
  for (int nt = 0; nt < 4; nt++){
    const int n = tileN + wn + nt * 16 + lr;
    #pragma unroll
    for (int mt = 0; mt < MT; mt++){
      #pragma unroll
      for (int r = 0; r < 4; r++){
        const int m = tileM + wm + mt * 16 + rq + r;
        float val = acc[mt][nt][r];
        if (EPI == 3){
          float res = residual[(long)tz * sRb + (long)m * N + n];
          ((float*)out0)[(long)tz * sOb + (long)m * N + n] = val + res;
        } else {  // EPI == 4
          if (bias) val += bias[m];
          long idx = (long)(n / seq) * ((long)M * seq) + (long)m * seq + (n % seq);
          ((u16*)out0)[idx] = f2b(val);
        }
      }
    }
  }
}

// ---------------- fused: bvec (256 blocks) + step 5 (256 blocks) ----------------
// Both depend only on prep's WkT/WqT outputs and were serial narrow launches
// (bvec ~3us alone; step 5 at 1 block/CU alone). Co-resident they overlap.
__global__ __launch_bounds__(256, 4)
void fused_bvec_s5(const u16* __restrict__ WkT_pair, const u16* __restrict__ WqT_pair,
                   const float* __restrict__ bq,
                   float* __restrict__ b_vec, float* __restrict__ Mt_part)
{
  __shared__ u16 sh[2 * BM * 64];   // 32 KB, gemm path only
  const int blk = blockIdx.x, t = threadIdx.x;
  if (blk < 256){
    // bvec: b[e] = sum_g Wk[g][e]*bq[g] from WkT_pair hi+lo
    const int wave = t >> 6, lane = t & 63;
    const int e = blk * 4 + wave;
    const u16* row = WkT_pair + (long)e * 2048;
    float acc = 0.f;
    #pragma unroll
    for (int ii = 0; ii < 2; ii++){
      int gi = lane * 2 + ii;
      const u16* p = row + gi * 16;
      #pragma unroll
      for (int j = 0; j < 8; j++)
        acc += (b2f(p[j]) + b2f(p[j + 8])) * bq[gi * 8 + j];
    }
    #pragma unroll
    for (int off = 32; off > 0; off >>= 1) acc += __shfl_xor(acc, off, 64);
    if (lane == 0) b_vec[e] = acc;
    return;
  }
  // step 5: Mt[e,f] partials, K split 4x256 — replica of grid (8,8,4) + xcd_remap
  const int b = blk - 256;
  const int rank = (b & 7) * 32 + (b >> 3);
  const int tz = rank >> 6, rem = rank & 63;
  gemm_nt_body<true, 2>(rem & 7, rem >> 3, tz, sh, sh + BM * 64,
                        WkT_pair, WqT_pair, nullptr, nullptr, Mt_part,
                        1024, 1024, 256, 1024, 512, 512, 1024L * 1024, 0, 2048);
}

// ---------------- fused: split q,k + kb (8192 blocks) + reduce_split (512) --------
// Tiny LDS only (R6 lesson: never give memory-bound blocks a 32KB allocation).
__global__ __launch_bounds__(256)
void fused_split_reduce(const float* __restrict__ q, const float* __restrict__ kk,
                        const float* __restrict__ b,
                        u16* __restrict__ q_pair, u16* __restrict__ k_pair,
                        float* __restrict__ kb,
                        const float* __restrict__ part, u16* __restrict__ out_pair,
                        long nper)
{
  __shared__ float red[4];
  const int blk = blockIdx.x, t = threadIdx.x;
  if (blk < 8192){
    const bool isK = blk >= 4096;
    const float* src = isK ? kk : q;
    u16* dst = isK ? k_pair : q_pair;
    long base = isK ? blk - 4096 : blk;
    long i = base * 256 + t;
    float4 x0 = ((const float4*)src)[2 * i];
    float4 x1 = ((const float4*)src)[2 * i + 1];
    float xs[8] = {x0.x, x0.y, x0.z, x0.w, x1.x, x1.y, x1.z, x1.w};
    u16x8 h, l;
    #pragma unroll
    for (int j = 0; j < 8; j++){ h[j] = f2b(xs[j]); l[j] = f2b(xs[j] - b2f(h[j])); }
    ((u16x8*)dst)[2 * i]     = h;
    ((u16x8*)dst)[2 * i + 1] = l;
    if (isK){
      const int f = (t & 127) * 8;
      float d = 0.f;
      #pragma unroll
      for (int j = 0; j < 8; j++) d += xs[j] * b[f + j];
      #pragma unroll
      for (int off = 32; off > 0; off >>= 1) d += __shfl_xor(d, off, 64);
      if ((t & 63) == 0) red[t >> 6] = d;
      __syncthreads();
      if (t == 0)   kb[base * 2]     = red[0] + red[1];
      if (t == 128) kb[base * 2 + 1] = red[2] + red[3];
    }
    return;
  }
  // reduce: 4 fp32 partials -> dual pair
  long i = (long)(blk - 8192) * 256 + t;
  float s[8];
  #pragma unroll
  for (int j = 0; j < 8; j++) s[j] = 0.f;
  #pragma unroll
  for (int z = 0; z < 4; z++){
    float4 a0 = ((const float4*)(part + z * nper))[2 * i];
    float4 a1 = ((const float4*)(part + z * nper))[2 * i + 1];
    s[0]+=a0.x; s[1]+=a0.y; s[2]+=a0.z; s[3]+=a0.w;
    s[4]+=a1.x; s[5]+=a1.y; s[6]+=a1.z; s[7]+=a1.w;
  }
  u16x8 h, l;
  #pragma unroll
  for (int j = 0; j < 8; j++){ h[j] = f2b(s[j]); l[j] = f2b(s[j] - b2f(h[j])); }
  long e = (i * 8) >> 10;
  long g = i & 127;
  u16* o = out_pair + e * 2048 + g * 16;
  *(u16x8*)o = h;
  *(u16x8*)(o + 8) = l;
}

// ---------------- fused steps 3+7: two independent 512-block GEMMs ----------------
// Each alone fills only 2 blocks/CU; fused 1024-block launch co-resides both at 4/CU.
// Step 3 (single) now uses the BK=64 two-panel body (half the barrier-pairs).
__global__ __launch_bounds__(256, 4)
void gemm_step37(const u16* __restrict__ Wv_b, const u16* __restrict__ v_b,
                 const float* __restrict__ bv, u16* __restrict__ vpT,
                 const u16* __restrict__ q_pair, const u16* __restrict__ Mt_pair,
                 u16* __restrict__ tmp_pair)
{
  __shared__ u16 sh[2 * BM * 64];   // 32 KB: dual uses [A|B]; single uses 2-panel A+B
  const int b = blockIdx.x, xcd = b & 7, i = b >> 3;
  if (i < 64){
    // step 3: vpT = Wv_b @ v_b^T + bv, EPI4, grid was (64, 8): tx = rank&63, ty = rank>>6
    const int rank = xcd * 64 + i;
    gemm_nt1_bk64<128, 4>(rank & 63, rank >> 6, 0, sh, sh + 2 * 128 * 32,
                          Wv_b, v_b, bv, nullptr, vpT,
                          1024, 8192, 1024, 1024, 0, 0, 0, 0, 2048);
  } else {
    // step 7: tmp_pair = q_pair @ Mt_pair^T, EPI0, grid was (8, 64): tx = rank&7, ty = rank>>3
    const int rank = xcd * 64 + (i - 64);
    gemm_nt_body<true, 0>(rank & 7, rank >> 3, 0, sh, sh + BM * 64,
                          q_pair, Mt_pair, nullptr, nullptr, tmp_pair,
                          8192, 1024, 1024, 1024, 0, 0, 0, 0, 2048);
  }
}

// ---------------- step 10: 64x128 single GEMM, BK=64 two-panel [R9] ---------------
// out[z][m][n] = sum_k attn[z][m][k] * vpT[z][n][k] + q[z][m][n]
// 1024 blocks = 4/CU (R7 win) + barrier-pairs 64 -> 32 (K=2048).  24 KB LDS.
__global__ __launch_bounds__(256, 4)
void gemm_nt64(const u16* __restrict__ A, const u16* __restrict__ Bm,
               const float* __restrict__ residual, float* __restrict__ out,
               int N, int K, int Krow, long sAb, long sBb, long sOb, long sRb)
{
  __shared__ u16 ldsA[2 * 64 * 32];    // 8 KB (2 panels)
  __shared__ u16 ldsB[2 * 128 * 32];   // 16 KB (2 panels)
  int tx, ty, tz; xcd_remap(tx, ty, tz);
  gemm_nt1_bk64<64, 3>(tx, ty, tz, ldsA, ldsB,
                       A, Bm, nullptr, residual, out,
                       0, N, K, Krow, sAb, sBb, sOb, sRb, 0);
}

// ---------------- row softmax: fp32 scores -> bf16 probs (n == 2048) ----------------
__global__ __launch_bounds__(256)
void softmax_kernel(const float* __restrict__ S, u16* __restrict__ P, int n){
  const long row = blockIdx.x;
  const float* r = S + row * (long)n;
  const int t = threadIdx.x;
  float v[8];
  float mx = -3.0e38f;
  #pragma unroll
  for (int i = 0; i < 8; i++){ v[i] = r[t + (i << 8)]; mx = fmaxf(mx, v[i]); }
  #pragma unroll
  for (int off = 32; off > 0; off >>= 1) mx = fmaxf(mx, __shfl_xor(mx, off, 64));
  __shared__ float red[8];
  const int wave = t >> 6;
  if ((t & 63) == 0) red[wave] = mx;
  __syncthreads();
  mx = fmaxf(fmaxf(red[0], red[1]), fmaxf(red[2], red[3]));
  float s = 0.f;
  #pragma unroll
  for (int i = 0; i < 8; i++){ v[i] = __expf(v[i] - mx); s += v[i]; }
  #pragma unroll
  for (int off = 32; off > 0; off >>= 1) s += __shfl_xor(s, off, 64);
  if ((t & 63) == 0) red[4 + wave] = s;
  __syncthreads();
  s = red[4] + red[5] + red[6] + red[7];
  const float inv = 1.f / s;
  u16* pr = P + row * (long)n;
  #pragma unroll
  for (int i = 0; i < 8; i++) pr[t + (i << 8)] = f2b(v[i] * inv);
}

extern "C" void kernel_launch(void* const* d_in, const int* in_sizes, int n_in,
                              void* d_out, int out_size, void* d_ws, size_t ws_size,
                              hipStream_t stream){
  (void)in_sizes; (void)n_in; (void)out_size; (void)ws_size;
  const float* q  = (const float*)d_in[0];
  const float* k  = (const float*)d_in[1];
  const float* v  = (const float*)d_in[2];
  const float* Wq = (const float*)d_in[3];
  const float* bq = (const float*)d_in[4];
  const float* Wk = (const float*)d_in[5];
  // bk enters only a row-constant term: softmax-invariant, dropped
  const float* Wv = (const float*)d_in[7];
  const float* bv = (const float*)d_in[8];
  float* out = (float*)d_out;

  const int B = 4, S = 2048, F = 1024;
  const long NSF = (long)B * S * F;   // 8 Mi
  const long NFF = (long)F * F;       // 1 Mi
  const long NSS = (long)B * S * S;   // 16 Mi

  char* w = (char*)d_ws;
  auto alloc = [&](long bytes) -> char* {
    char* p = w; w += (bytes + 255) & ~(long)255; return p;
  };
  // persistent
  u16*   tmp_pair = (u16*)alloc(2 * NSF * 2);   // (q M^T) dual pair, 33.5 MB
  u16*   k_pair   = (u16*)alloc(2 * NSF * 2);   // raw k dual pair,   33.5 MB
  u16*   vpT      = (u16*)alloc(NSF * 2);       // 16.8 MB
  float* kb       = (float*)alloc((long)B * S * 4);
  // zone2 (100.7 MB): scores+attn alias the phase-1 temporaries
  char* zone2 = alloc(NSS * 2 + NSS * 4);
  u16*   attn   = (u16*)zone2;
  float* scores = (float*)(zone2 + NSS * 2);
  // phase-1 occupants (dead before their aliasing writer runs):
  u16*   q_pair   = (u16*)zone2;                        // == attn region
  char*  z3       = zone2 + NSS * 2;                    // == scores region
  u16*   v_b      = (u16*)z3;                           // 16.8 MB
  u16*   Wv_b     = (u16*)(z3 + NSF * 2);               // 2.1 MB
  u16*   WqT_pair = (u16*)(z3 + NSF * 2 + NFF * 2);     // 4.2 MB
  u16*   WkT_pair = WqT_pair + 2 * NFF;                 // 4.2 MB
  float* b_vec    = (float*)(WkT_pair + 2 * NFF);       // 4 KB
  float* Mt_part  = (float*)((char*)b_vec + 4096);      // 4 x 4.2 MB
  u16*   Mt_pair  = (u16*)((char*)Mt_part + 4 * NFF * 4);

  dim3 blk(256);

  // 1) prep: v/Wv split, Wq/Wk transpose+dual-split
  prep_kernel<<<dim3(5120), blk, 0, stream>>>(
      v, Wv, Wq, Wk, v_b, Wv_b, WqT_pair, WkT_pair);

  // 2+5 fused) b_vec = Wk^T bq  AND  Mt partials (co-resident)
  fused_bvec_s5<<<dim3(512), blk, 0, stream>>>(
      WkT_pair, WqT_pair, bq, b_vec, Mt_part);

  // 4+6 fused) split q,k (dual) + kb  AND  Mt_pair = dual-split(sum of partials)
  fused_split_reduce<<<dim3(8704), blk, 0, stream>>>(
      q, k, b_vec, q_pair, k_pair, kb, Mt_part, Mt_pair, NFF);

  // 3+7 fused) vpT = Wv v^T + bv  AND  tmp = q @ Mt^T (co-resident 4 blocks/CU)
  gemm_step37<<<dim3(1024), blk, 0, stream>>>(
      Wv_b, v_b, bv, vpT, q_pair, Mt_pair, tmp_pair);

  // 8) scores[z] = tmp[z] @ k[z]^T + kb[z][:]  (fp32) — verified 128^2 4-block/CU
  gemm_nt<true, 2><<<dim3(S / BN, S / BM, B), blk, 0, stream>>>(
      tmp_pair, k_pair, kb, nullptr, scores,
      S, S, F, F, (long)S * 2 * F, (long)S * 2 * F, (long)S * S, 0, S);

  // 9) attn = softmax(scores) (bf16)
  softmax_kernel<<<dim3(B * S), blk, 0, stream>>>(scores, attn, S);

  // 10) out[z] = attn[z] @ vp[z] + q[z] — 64x128 tile, BK=64, 4/CU
  gemm_nt64<<<dim3(F / 128, S / 64, B), blk, 0, stream>>>(
      attn, vpT, q, out,
      F, S, S, (long)S * S, (long)F * S, (long)S * F, (long)S * F);
}